// Round 2
// baseline (668.288 us; speedup 1.0000x reference)
//
#include <hip/hip_runtime.h>
#include <hip/hip_bf16.h>

typedef __attribute__((ext_vector_type(8))) short short8;
typedef __attribute__((ext_vector_type(4))) float float4v;
typedef __attribute__((ext_vector_type(4))) unsigned short ushort4v;

#define LQ 512
#define NB 4
#define LKV 4096
#define E 256
#define NH 8
#define HD 32
#define NLAYER 4
#define QSCALE 0.17677669529663687f
#define SPLITS 4
#define KSPAN (LKV / SPLITS)

__device__ __forceinline__ unsigned short f2bf(float f) {
    union { float f; unsigned int i; } x; x.f = f;
    unsigned int r = x.i + 0x7fffu + ((x.i >> 16) & 1u);
    return (unsigned short)(r >> 16);
}
__device__ __forceinline__ unsigned int pack2(float a, float b) {
    return (unsigned int)f2bf(a) | ((unsigned int)f2bf(b) << 16);
}
__device__ __forceinline__ float bfbits2f(unsigned short u) {
    union { unsigned int i; float f; } x; x.i = ((unsigned int)u) << 16; return x.f;
}
__device__ __forceinline__ float4v mfma16(short8 a, short8 b, float4v c) {
    return __builtin_amdgcn_mfma_f32_16x16x32_bf16(a, b, c, 0, 0, 0);
}
__device__ __forceinline__ uint4 pack8(const float* p) {
    float4 a0 = *(const float4*)p;
    float4 a1 = *(const float4*)(p + 4);
    uint4 v;
    v.x = pack2(a0.x, a0.y); v.y = pack2(a0.z, a0.w);
    v.z = pack2(a1.x, a1.y); v.w = pack2(a1.z, a1.w);
    return v;
}

// ---------------- init: cur = query (f32 copy) ----------------
__global__ void init_cur(const float* __restrict__ q, float* __restrict__ cur) {
    int i = blockIdx.x * 256 + threadIdx.x;
    cur[i] = q[i];
}

// ---------------- generic GEMM: out = A(f32)@W^T + bias (+res)(relu) -> f32 ----------------
// Tile 64x64, block 256 = 4 waves (2x2), K-loop 8x32, mfma 16x16x32 bf16.
__global__ __launch_bounds__(256) void gemm_k(
        const float* __restrict__ A, const float* __restrict__ W,
        const float* __restrict__ bias, const float* __restrict__ res,
        float* __restrict__ out, int relu) {
    __shared__ unsigned short sA[64 * 40];
    __shared__ unsigned short sB[64 * 40];
    const int t = threadIdx.x;
    const int lane = t & 63, wave = t >> 6, quad = lane >> 4, lid = lane & 15;
    const int wr = wave >> 1, wc = wave & 1;
    const int row0 = blockIdx.x * 64, col0 = blockIdx.y * 64;
    const int sr = t >> 2, sk = (t & 3) * 8;
    float4v acc[2][2];
    for (int i = 0; i < 2; i++) for (int j = 0; j < 2; j++) acc[i][j] = (float4v){0.f, 0.f, 0.f, 0.f};
    for (int k0 = 0; k0 < E; k0 += 32) {
        uint4 av = pack8(A + (long)(row0 + sr) * E + k0 + sk);
        uint4 bv = pack8(W + (long)(col0 + sr) * E + k0 + sk);
        __syncthreads();
        *(uint4*)&sA[sr * 40 + sk] = av;
        *(uint4*)&sB[sr * 40 + sk] = bv;
        __syncthreads();
        short8 af0 = *(const short8*)&sA[(wr * 32 + lid) * 40 + quad * 8];
        short8 af1 = *(const short8*)&sA[(wr * 32 + 16 + lid) * 40 + quad * 8];
        short8 bf0 = *(const short8*)&sB[(wc * 32 + lid) * 40 + quad * 8];
        short8 bf1 = *(const short8*)&sB[(wc * 32 + 16 + lid) * 40 + quad * 8];
        acc[0][0] = mfma16(af0, bf0, acc[0][0]);
        acc[0][1] = mfma16(af0, bf1, acc[0][1]);
        acc[1][0] = mfma16(af1, bf0, acc[1][0]);
        acc[1][1] = mfma16(af1, bf1, acc[1][1]);
    }
#pragma unroll
    for (int mt = 0; mt < 2; mt++)
#pragma unroll
        for (int nt = 0; nt < 2; nt++)
#pragma unroll
            for (int r = 0; r < 4; r++) {
                int grow = row0 + wr * 32 + mt * 16 + quad * 4 + r;
                int gcol = col0 + wc * 32 + nt * 16 + lid;
                float v = acc[mt][nt][r] + bias[gcol];
                if (res) v += res[(long)grow * E + gcol];
                if (relu) v = fmaxf(v, 0.f);
                out[(long)grow * E + gcol] = v;
            }
}

// ---------------- QKV projection + rotary epilogue ----------------
// QMODE: A=cur(f32) rows=2048, cols=256 (Wq), scale+rotary(query_pos) -> qbuf[b][h][lq][hd] bf16
// !QMODE: A=value(f32) rows=16384, cols=512 (Wk|Wv); k: rotary(value_pos) -> kbuf[b][h][pos][hd];
//         v -> vT[b][h][hd][pos] (pre-transposed for attention's V B-frags)
template <bool QMODE>
__global__ __launch_bounds__(256) void qkv_gemm(
        const float* __restrict__ A, const float* __restrict__ W,
        const float* __restrict__ bias, const float* __restrict__ pos,
        unsigned short* __restrict__ qkout, unsigned short* __restrict__ vtout) {
    const int L = QMODE ? LQ : LKV;
    __shared__ unsigned short sA[64 * 40];
    __shared__ unsigned short sB[64 * 40];
    const int t = threadIdx.x;
    const int lane = t & 63, wave = t >> 6, quad = lane >> 4, lid = lane & 15;
    const int wr = wave >> 1, wc = wave & 1;
    const int row0 = blockIdx.x * 64, col0 = blockIdx.y * 64;
    const int sr = t >> 2, sk = (t & 3) * 8;
    float4v acc[2][2];
    for (int i = 0; i < 2; i++) for (int j = 0; j < 2; j++) acc[i][j] = (float4v){0.f, 0.f, 0.f, 0.f};
    for (int k0 = 0; k0 < E; k0 += 32) {
        uint4 av = pack8(A + (long)(row0 + sr) * E + k0 + sk);
        uint4 bv = pack8(W + (long)(col0 + sr) * E + k0 + sk);
        __syncthreads();
        *(uint4*)&sA[sr * 40 + sk] = av;
        *(uint4*)&sB[sr * 40 + sk] = bv;
        __syncthreads();
        short8 af0 = *(const short8*)&sA[(wr * 32 + lid) * 40 + quad * 8];
        short8 af1 = *(const short8*)&sA[(wr * 32 + 16 + lid) * 40 + quad * 8];
        short8 bf0 = *(const short8*)&sB[(wc * 32 + lid) * 40 + quad * 8];
        short8 bf1 = *(const short8*)&sB[(wc * 32 + 16 + lid) * 40 + quad * 8];
        acc[0][0] = mfma16(af0, bf0, acc[0][0]);
        acc[0][1] = mfma16(af0, bf1, acc[0][1]);
        acc[1][0] = mfma16(af1, bf0, acc[1][0]);
        acc[1][1] = mfma16(af1, bf1, acc[1][1]);
    }
#pragma unroll
    for (int mt = 0; mt < 2; mt++)
#pragma unroll
        for (int nt = 0; nt < 2; nt++)
#pragma unroll
            for (int r = 0; r < 4; r++) {
                int grow = row0 + wr * 32 + mt * 16 + quad * 4 + r;
                int gcol = col0 + wc * 32 + nt * 16 + lid;
                float v = acc[mt][nt][r] + bias[gcol];
                if (QMODE) v *= QSCALE;
                int seq = grow >> 2, b = grow & 3;
                if (QMODE || gcol < E) {  // wave-uniform (tile granularity 16, boundary 256)
                    int c = gcol;
                    long pidx = (((long)b * L + seq) * E + c) * 2;
                    float cv = pos[pidx], sv = pos[pidx + 1];
                    float p = __shfl_xor(v, 1);
                    float x2 = (c & 1) ? p : -p;
                    float rv = v * cv + x2 * sv;
                    qkout[(((long)b * NH + (c >> 5)) * L + seq) * HD + (c & 31)] = f2bf(rv);
                } else {
                    int c = gcol - E;
                    vtout[(((long)b * NH + (c >> 5)) * HD + (c & 31)) * (long)LKV + seq] = f2bf(v);
                }
            }
}

// ---------------- flash attention (split-KV), mfma 16x16x32 ----------------
// grid (LQ/64, B*H, SPLITS), block 256. Each wave owns 16 q-rows; block stages 64-key K/V chunks.
__global__ __launch_bounds__(256) void attn_k(
        const unsigned short* __restrict__ qb, const unsigned short* __restrict__ kb,
        const unsigned short* __restrict__ vtb, float* __restrict__ Opart,
        float* __restrict__ mpart, float* __restrict__ lpart) {
    __shared__ unsigned short sK[64 * 40];
    __shared__ unsigned short sVT[32 * 88];
    __shared__ unsigned short sPT[4 * 64 * 20];
    const int t = threadIdx.x;
    const int lane = t & 63, wave = t >> 6, quad = lane >> 4, lid = lane & 15;
    const int qt0 = blockIdx.x * 64;
    const int bh = blockIdx.y;
    const int split = blockIdx.z;
    const int key0 = split * KSPAN;
    const unsigned short* kbase = kb + (long)bh * LKV * HD;
    const unsigned short* vbase = vtb + (long)bh * HD * LKV;
    const int qrow_a = qt0 + wave * 16 + lid;
    short8 aq = *(const short8*)(qb + ((long)bh * LQ + qrow_a) * HD + quad * 8);
    float4v o0 = (float4v){0.f, 0.f, 0.f, 0.f}, o1 = (float4v){0.f, 0.f, 0.f, 0.f};
    float m[4] = {-1e30f, -1e30f, -1e30f, -1e30f};
    float l[4] = {0.f, 0.f, 0.f, 0.f};
    const int skr = t >> 2, skk = (t & 3) * 8;
    const int svd = t >> 3, svp = (t & 7) * 8;
    unsigned short* myPT = &sPT[wave * 1280];
    for (int ck = key0; ck < key0 + KSPAN; ck += 64) {
        uint4 kv = *(const uint4*)(kbase + (long)(ck + skr) * HD + skk);
        uint4 vv = *(const uint4*)(vbase + (long)svd * LKV + ck + svp);
        __syncthreads();
        *(uint4*)&sK[skr * 40 + skk] = kv;
        *(uint4*)&sVT[svd * 88 + svp] = vv;
        __syncthreads();
        float4v sf[4];
#pragma unroll
        for (int f = 0; f < 4; f++) {
            short8 bk = *(const short8*)&sK[(f * 16 + lid) * 40 + quad * 8];
            float4v z = (float4v){0.f, 0.f, 0.f, 0.f};
            sf[f] = mfma16(aq, bk, z);
        }
#pragma unroll
        for (int r = 0; r < 4; r++) {
            float mx = fmaxf(fmaxf(sf[0][r], sf[1][r]), fmaxf(sf[2][r], sf[3][r]));
#pragma unroll
            for (int d = 1; d < 16; d <<= 1) mx = fmaxf(mx, __shfl_xor(mx, d));
            float mnew = fmaxf(m[r], mx);
            float alpha = __expf(m[r] - mnew);
            m[r] = mnew;
            float rs = 0.f;
#pragma unroll
            for (int f = 0; f < 4; f++) { sf[f][r] = __expf(sf[f][r] - mnew); rs += sf[f][r]; }
#pragma unroll
            for (int d = 1; d < 16; d <<= 1) rs += __shfl_xor(rs, d);
            l[r] = l[r] * alpha + rs;
            o0[r] *= alpha; o1[r] *= alpha;
        }
        // P -> LDS transposed: sPT[key][q], b64 packed writes (4 q-rows per lane)
#pragma unroll
        for (int f = 0; f < 4; f++) {
            ushort4v pk;
            pk.x = f2bf(sf[f][0]); pk.y = f2bf(sf[f][1]);
            pk.z = f2bf(sf[f][2]); pk.w = f2bf(sf[f][3]);
            *(ushort4v*)&myPT[(f * 16 + lid) * 20 + quad * 4] = pk;
        }
        __syncthreads();
#pragma unroll
        for (int kb2 = 0; kb2 < 64; kb2 += 32) {
            short8 ap;
#pragma unroll
            for (int j = 0; j < 8; j++)
                ap[j] = (short)myPT[(kb2 + quad * 8 + j) * 20 + lid];
            short8 bv0 = *(const short8*)&sVT[lid * 88 + kb2 + quad * 8];
            short8 bv1 = *(const short8*)&sVT[(16 + lid) * 88 + kb2 + quad * 8];
            o0 = mfma16(ap, bv0, o0);
            o1 = mfma16(ap, bv1, o1);
        }
    }
#pragma unroll
    for (int r = 0; r < 4; r++) {
        int qr = qt0 + wave * 16 + quad * 4 + r;
        long orow = ((long)split * 32 + bh) * LQ + qr;
        Opart[orow * HD + lid] = o0[r];
        Opart[orow * HD + 16 + lid] = o1[r];
        if (lid == 0) { mpart[orow] = m[r]; lpart[orow] = l[r]; }
    }
}

// ---------------- combine split-KV partials -> o[lq*B+b][h*32+d] f32 ----------------
__global__ void attn_combine(const float* __restrict__ Opart, const float* __restrict__ mpart,
                             const float* __restrict__ lpart, float* __restrict__ o) {
    const int t = threadIdx.x;
    const int r = blockIdx.x * 8 + (t >> 5);   // r = bh*512 + qrow, 16384 total
    const int d = t & 31;
    float M = -1e30f;
#pragma unroll
    for (int s = 0; s < SPLITS; s++) M = fmaxf(M, mpart[s * 16384 + r]);
    float L = 0.f, acc = 0.f;
#pragma unroll
    for (int s = 0; s < SPLITS; s++) {
        float w = __expf(mpart[s * 16384 + r] - M);
        L += w * lpart[s * 16384 + r];
        acc += w * Opart[(long)(s * 16384 + r) * HD + d];
    }
    const int bh = r >> 9, qrow = r & 511;
    const int b = bh >> 3, h = bh & 7;
    o[(long)(qrow * NB + b) * E + h * HD + d] = acc / L;
}

// ---------------- LayerNorm over E=256: block 256 = 4 rows x 64 lanes ----------------
__global__ void ln_k(const float* __restrict__ in, const float* __restrict__ g,
                     const float* __restrict__ b, float* __restrict__ out,
                     float* __restrict__ out2) {
    const int t = threadIdx.x;
    const int lane = t & 63;
    const int row = blockIdx.x * 4 + (t >> 6);
    const float4 v = *(const float4*)&in[(long)row * E + lane * 4];
    float s = v.x + v.y + v.z + v.w;
#pragma unroll
    for (int d = 1; d < 64; d <<= 1) s += __shfl_xor(s, d);
    const float mean = s * (1.f / 256.f);
    float dx0 = v.x - mean, dx1 = v.y - mean, dx2 = v.z - mean, dx3 = v.w - mean;
    float ss = dx0 * dx0 + dx1 * dx1 + dx2 * dx2 + dx3 * dx3;
#pragma unroll
    for (int d = 1; d < 64; d <<= 1) ss += __shfl_xor(ss, d);
    const float rstd = rsqrtf(ss * (1.f / 256.f) + 1e-5f);
    const int c0 = lane * 4;
    float4 gg = *(const float4*)&g[c0];
    float4 bb = *(const float4*)&b[c0];
    float4 ov;
    ov.x = dx0 * rstd * gg.x + bb.x;
    ov.y = dx1 * rstd * gg.y + bb.y;
    ov.z = dx2 * rstd * gg.z + bb.z;
    ov.w = dx3 * rstd * gg.w + bb.w;
    *(float4*)&out[(long)row * E + c0] = ov;
    if (out2) *(float4*)&out2[(long)row * E + c0] = ov;
}

extern "C" void kernel_launch(void* const* d_in, const int* in_sizes, int n_in,
                              void* d_out, int out_size, void* d_ws, size_t ws_size,
                              hipStream_t stream) {
    (void)in_sizes; (void)n_in; (void)out_size; (void)ws_size;
    const float* query = (const float*)d_in[0];
    const float* value = (const float*)d_in[1];
    const float* qpos  = (const float*)d_in[2];
    const float* vpos  = (const float*)d_in[3];
    const float* Wqkv  = (const float*)d_in[4];
    const float* bqkv  = (const float*)d_in[5];
    const float* Wo    = (const float*)d_in[6];
    const float* bo    = (const float*)d_in[7];
    const float* g1    = (const float*)d_in[8];
    const float* be1   = (const float*)d_in[9];
    const float* W1    = (const float*)d_in[10];
    const float* b1    = (const float*)d_in[11];
    const float* W2    = (const float*)d_in[12];
    const float* b2    = (const float*)d_in[13];
    const float* g2    = (const float*)d_in[14];
    const float* be2   = (const float*)d_in[15];
    float* outp = (float*)d_out;

    char* w = (char*)d_ws;
    float*          cur   = (float*)(w + 0);                    // 2 MB  [2048][256] f32
    unsigned short* qbuf  = (unsigned short*)(w + (2l  << 20)); // 1 MB  [B][H][LQ][HD] bf16
    unsigned short* kbuf  = (unsigned short*)(w + (3l  << 20)); // 8 MB  [B][H][LKV][HD] bf16
    unsigned short* vtb   = (unsigned short*)(w + (11l << 20)); // 8 MB  [B][H][HD][LKV] bf16
    float*          obuf  = (float*)(w + (19l << 20));          // 2 MB
    float*          tmp   = (float*)(w + (21l << 20));          // 2 MB
    float*          xb    = (float*)(w + (23l << 20));          // 2 MB
    float*          h1b   = (float*)(w + (25l << 20));          // 2 MB
    float*          Opart = (float*)(w + (27l << 20));          // 8 MB  [S][32][512][32] f32
    float*          mp    = (float*)(w + (35l << 20));          // 256 KB
    float*          lp    = (float*)(w + (35l << 20) + (256l << 10));

    init_cur<<<2048, 256, 0, stream>>>(query, cur);
    for (int layer = 0; layer < NLAYER; layer++) {
        const float* Wl = Wqkv + (long)layer * 768 * 256;
        const float* bl = bqkv + (long)layer * 768;
        qkv_gemm<true><<<dim3(32, 4), 256, 0, stream>>>(cur, Wl, bl, qpos, qbuf, nullptr);
        qkv_gemm<false><<<dim3(256, 8), 256, 0, stream>>>(value, Wl + 256 * 256, bl + 256, vpos, kbuf, vtb);
        attn_k<<<dim3(8, 32, SPLITS), 256, 0, stream>>>(qbuf, kbuf, vtb, Opart, mp, lp);
        attn_combine<<<2048, 256, 0, stream>>>(Opart, mp, lp, obuf);
        gemm_k<<<dim3(32, 4), 256, 0, stream>>>(obuf, Wo + layer * 65536, bo + layer * 256, cur, tmp, 0);
        ln_k<<<512, 256, 0, stream>>>(tmp, g1 + layer * 256, be1 + layer * 256, xb, nullptr);
        gemm_k<<<dim3(32, 4), 256, 0, stream>>>(xb, W1 + layer * 65536, b1 + layer * 256, nullptr, h1b, 1);
        gemm_k<<<dim3(32, 4), 256, 0, stream>>>(h1b, W2 + layer * 65536, b2 + layer * 256, xb, tmp, 0);
        ln_k<<<512, 256, 0, stream>>>(tmp, g2 + layer * 256, be2 + layer * 256, cur,
                                      outp + (long)layer * LQ * NB * E);
    }
}

// Round 3
// 564.433 us; speedup vs baseline: 1.1840x; 1.1840x over previous
//
#include <hip/hip_runtime.h>
#include <hip/hip_bf16.h>

typedef __attribute__((ext_vector_type(8))) short short8;
typedef __attribute__((ext_vector_type(4))) float float4v;
typedef __attribute__((ext_vector_type(4))) unsigned short ushort4v;

#define LQ 512
#define NB 4
#define LKV 4096
#define E 256
#define NH 8
#define HD 32
#define NLAYER 4
#define QSCALE 0.17677669529663687f
#define SPLITS 4
#define KSPAN (LKV / SPLITS)
#define QT 128   // q rows per attn block
#define CK 128   // keys per attn chunk

__device__ __forceinline__ unsigned short f2bf(float f) {
    union { float f; unsigned int i; } x; x.f = f;
    unsigned int r = x.i + 0x7fffu + ((x.i >> 16) & 1u);
    return (unsigned short)(r >> 16);
}
__device__ __forceinline__ unsigned int pack2(float a, float b) {
    return (unsigned int)f2bf(a) | ((unsigned int)f2bf(b) << 16);
}
__device__ __forceinline__ unsigned int pack2_rtz(float a, float b) {
    union { float f; unsigned int i; } xa, xb; xa.f = a; xb.f = b;
    return __builtin_amdgcn_perm(xb.i, xa.i, 0x07060302u);  // (hi16(a) | hi16(b)<<16)
}
__device__ __forceinline__ float4v mfma16(short8 a, short8 b, float4v c) {
    return __builtin_amdgcn_mfma_f32_16x16x32_bf16(a, b, c, 0, 0, 0);
}
__device__ __forceinline__ uint4 pack8(const float* p) {
    float4 a0 = *(const float4*)p;
    float4 a1 = *(const float4*)(p + 4);
    uint4 v;
    v.x = pack2(a0.x, a0.y); v.y = pack2(a0.z, a0.w);
    v.z = pack2(a1.x, a1.y); v.w = pack2(a1.z, a1.w);
    return v;
}

// ---------------- init: cur = query (f32 copy) ----------------
__global__ void init_cur(const float* __restrict__ q, float* __restrict__ cur) {
    int i = blockIdx.x * 256 + threadIdx.x;
    cur[i] = q[i];
}

// ---------------- small GEMM: out = A@W^T + bias (+res)(relu), M=32/N=64 tile, full-K LDS ----------------
__global__ __launch_bounds__(256) void gemm_k(
        const float* __restrict__ A, const float* __restrict__ W,
        const float* __restrict__ bias, const float* __restrict__ res,
        float* __restrict__ out, int relu) {
    __shared__ unsigned short sA[32 * 264];
    __shared__ unsigned short sB[64 * 264];
    const int t = threadIdx.x;
    const int lane = t & 63, wave = t >> 6, quad = lane >> 4, lid = lane & 15;
    const int row0 = blockIdx.x * 32, col0 = blockIdx.y * 64;
    {   // stage A: 32 rows x 256 K
        int r = t >> 3, ks = (t & 7) * 32;
        const float* ap = A + (long)(row0 + r) * E + ks;
#pragma unroll
        for (int i = 0; i < 4; i++)
            *(uint4*)&sA[r * 264 + ks + i * 8] = pack8(ap + i * 8);
    }
    {   // stage B: 64 rows x 256 K
        int r = t >> 2, ks = (t & 3) * 64;
        const float* wp = W + (long)(col0 + r) * E + ks;
#pragma unroll
        for (int i = 0; i < 8; i++)
            *(uint4*)&sB[r * 264 + ks + i * 8] = pack8(wp + i * 8);
    }
    __syncthreads();
    float4v acc[2];
    acc[0] = (float4v){0.f, 0.f, 0.f, 0.f};
    acc[1] = (float4v){0.f, 0.f, 0.f, 0.f};
#pragma unroll
    for (int k0 = 0; k0 < E; k0 += 32) {
        short8 bf = *(const short8*)&sB[(wave * 16 + lid) * 264 + k0 + quad * 8];
        short8 af0 = *(const short8*)&sA[(lid) * 264 + k0 + quad * 8];
        short8 af1 = *(const short8*)&sA[(16 + lid) * 264 + k0 + quad * 8];
        acc[0] = mfma16(af0, bf, acc[0]);
        acc[1] = mfma16(af1, bf, acc[1]);
    }
#pragma unroll
    for (int mt = 0; mt < 2; mt++)
#pragma unroll
        for (int r = 0; r < 4; r++) {
            int grow = row0 + mt * 16 + quad * 4 + r;
            int gcol = col0 + wave * 16 + lid;
            float v = acc[mt][r] + bias[gcol];
            if (res) v += res[(long)grow * E + gcol];
            if (relu) v = fmaxf(v, 0.f);
            out[(long)grow * E + gcol] = v;
        }
}

// ---------------- Q projection + scale + rotary -> qbuf[b][h][lq][hd] bf16 ----------------
__global__ __launch_bounds__(256) void qkv_q(
        const float* __restrict__ A, const float* __restrict__ W,
        const float* __restrict__ bias, const float* __restrict__ pos,
        unsigned short* __restrict__ qkout) {
    __shared__ unsigned short sA[64 * 40];
    __shared__ unsigned short sB[64 * 40];
    const int t = threadIdx.x;
    const int lane = t & 63, wave = t >> 6, quad = lane >> 4, lid = lane & 15;
    const int wr = wave >> 1, wc = wave & 1;
    const int row0 = blockIdx.x * 64, col0 = blockIdx.y * 64;
    const int sr = t >> 2, sk = (t & 3) * 8;
    float4v acc[2][2];
    for (int i = 0; i < 2; i++) for (int j = 0; j < 2; j++) acc[i][j] = (float4v){0.f, 0.f, 0.f, 0.f};
    for (int k0 = 0; k0 < E; k0 += 32) {
        uint4 av = pack8(A + (long)(row0 + sr) * E + k0 + sk);
        uint4 bv = pack8(W + (long)(col0 + sr) * E + k0 + sk);
        __syncthreads();
        *(uint4*)&sA[sr * 40 + sk] = av;
        *(uint4*)&sB[sr * 40 + sk] = bv;
        __syncthreads();
        short8 af0 = *(const short8*)&sA[(wr * 32 + lid) * 40 + quad * 8];
        short8 af1 = *(const short8*)&sA[(wr * 32 + 16 + lid) * 40 + quad * 8];
        short8 bf0 = *(const short8*)&sB[(wc * 32 + lid) * 40 + quad * 8];
        short8 bf1 = *(const short8*)&sB[(wc * 32 + 16 + lid) * 40 + quad * 8];
        acc[0][0] = mfma16(af0, bf0, acc[0][0]);
        acc[0][1] = mfma16(af0, bf1, acc[0][1]);
        acc[1][0] = mfma16(af1, bf0, acc[1][0]);
        acc[1][1] = mfma16(af1, bf1, acc[1][1]);
    }
#pragma unroll
    for (int mt = 0; mt < 2; mt++)
#pragma unroll
        for (int nt = 0; nt < 2; nt++)
#pragma unroll
            for (int r = 0; r < 4; r++) {
                int grow = row0 + wr * 32 + mt * 16 + quad * 4 + r;
                int gcol = col0 + wc * 32 + nt * 16 + lid;
                float v = (acc[mt][nt][r] + bias[gcol]) * QSCALE;
                int seq = grow >> 2, b = grow & 3;
                int c = gcol;
                long pidx = (((long)b * LQ + seq) * E + c) * 2;
                float2 cs = *(const float2*)&pos[pidx];
                float p = __shfl_xor(v, 1);
                float x2 = (c & 1) ? p : -p;
                float rv = v * cs.x + x2 * cs.y;
                qkout[(((long)b * NH + (c >> 5)) * LQ + seq) * HD + (c & 31)] = f2bf(rv);
            }
}

// ---------------- KV projection: A=value staged once, loop over 8 col chunks of Wk|Wv ----------------
// grid 256 (row tiles of 64), block 512 = 8 waves (2 m-halves x 4 n-quarters).
// k (cols<256): rotary(value_pos) -> kbuf[b][h][pos][hd]; v: -> vtb[b][h][hd][pos]
__global__ __launch_bounds__(512) void qkv_kv(
        const float* __restrict__ A, const float* __restrict__ W,
        const float* __restrict__ bias, const float* __restrict__ pos,
        unsigned short* __restrict__ kout, unsigned short* __restrict__ vtout) {
    __shared__ unsigned short sA[64 * 264];
    __shared__ unsigned short sB[64 * 264];
    const int t = threadIdx.x;
    const int lane = t & 63, wave = t >> 6, quad = lane >> 4, lid = lane & 15;
    const int wr = wave >> 2, wc = wave & 3;
    const int row0 = blockIdx.x * 64;
    {   // stage A once: 64 rows x 256 K  (512 thr x 32 elems)
        int r = t >> 3, ks = (t & 7) * 32;
        const float* ap = A + (long)(row0 + r) * E + ks;
#pragma unroll
        for (int i = 0; i < 4; i++)
            *(uint4*)&sA[r * 264 + ks + i * 8] = pack8(ap + i * 8);
    }
    const int sbr = t >> 3, sbk = (t & 7) * 32;
    for (int nc = 0; nc < 8; nc++) {
        const int col0 = nc * 64;
        uint4 wreg[4];
        const float* wp = W + (long)(col0 + sbr) * E + sbk;
#pragma unroll
        for (int i = 0; i < 4; i++) wreg[i] = pack8(wp + i * 8);
        __syncthreads();   // prev chunk's compute done (and sA staged, first iter)
#pragma unroll
        for (int i = 0; i < 4; i++) *(uint4*)&sB[sbr * 264 + sbk + i * 8] = wreg[i];
        __syncthreads();
        float4v acc[2];
        acc[0] = (float4v){0.f, 0.f, 0.f, 0.f};
        acc[1] = (float4v){0.f, 0.f, 0.f, 0.f};
#pragma unroll
        for (int k0 = 0; k0 < E; k0 += 32) {
            short8 bf = *(const short8*)&sB[(wc * 16 + lid) * 264 + k0 + quad * 8];
            short8 af0 = *(const short8*)&sA[(wr * 32 + lid) * 264 + k0 + quad * 8];
            short8 af1 = *(const short8*)&sA[(wr * 32 + 16 + lid) * 264 + k0 + quad * 8];
            acc[0] = mfma16(af0, bf, acc[0]);
            acc[1] = mfma16(af1, bf, acc[1]);
        }
#pragma unroll
        for (int mt = 0; mt < 2; mt++)
#pragma unroll
            for (int r = 0; r < 4; r++) {
                int grow = row0 + wr * 32 + mt * 16 + quad * 4 + r;
                int gcol = col0 + wc * 16 + lid;
                float v = acc[mt][r] + bias[gcol];
                int seq = grow >> 2, b = grow & 3;
                if (gcol < E) {  // K half: rotary (wave-uniform: col chunks of 64)
                    int c = gcol;
                    long pidx = (((long)b * LKV + seq) * E + c) * 2;
                    float2 cs = *(const float2*)&pos[pidx];
                    float p = __shfl_xor(v, 1);
                    float x2 = (c & 1) ? p : -p;
                    float rv = v * cs.x + x2 * cs.y;
                    kout[(((long)b * NH + (c >> 5)) * LKV + seq) * HD + (c & 31)] = f2bf(rv);
                } else {         // V half: store transposed
                    int c = gcol - E;
                    vtout[(((long)b * NH + (c >> 5)) * HD + (c & 31)) * (long)LKV + seq] = f2bf(v);
                }
            }
    }
}

// ---------------- flash attention, split-KV, NO online max (scores bounded) ----------------
// grid (LQ/QT=4, 32 bh, SPLITS), block 256 = 4 waves, 32 q/wave, CK=128-key chunks.
__global__ __launch_bounds__(256) void attn_k(
        const unsigned short* __restrict__ qb, const unsigned short* __restrict__ kb,
        const unsigned short* __restrict__ vtb, float* __restrict__ Opart,
        float* __restrict__ lpart) {
    __shared__ unsigned short sK[CK * 40];        // [key][hd]
    __shared__ unsigned short sVT[32 * 136];      // [hd][key]
    __shared__ unsigned short sPT[4 * CK * 36];   // per-wave [key][q(32)+pad]
    const int t = threadIdx.x;
    const int lane = t & 63, wave = t >> 6, quad = lane >> 4, lid = lane & 15;
    const int qt0 = blockIdx.x * QT;
    const int bh = blockIdx.y;
    const int key0 = blockIdx.z * KSPAN;
    const unsigned short* kbase = kb + (long)bh * LKV * HD;
    const unsigned short* vbase = vtb + (long)bh * HD * LKV;
    short8 aq[2];
#pragma unroll
    for (int mf = 0; mf < 2; mf++)
        aq[mf] = *(const short8*)(qb + ((long)bh * LQ + qt0 + wave * 32 + mf * 16 + lid) * HD + quad * 8);
    float4v o[2][2];
#pragma unroll
    for (int i = 0; i < 2; i++) for (int j = 0; j < 2; j++) o[i][j] = (float4v){0.f, 0.f, 0.f, 0.f};
    float l[8] = {0.f, 0.f, 0.f, 0.f, 0.f, 0.f, 0.f, 0.f};
    const int krow = t >> 1, khalf = (t & 1) * 16;
    const int vrow = t >> 3, vkoff = (t & 7) * 16;
    unsigned short* myPT = &sPT[wave * CK * 36];
    for (int ck = key0; ck < key0 + KSPAN; ck += CK) {
        uint4 kv0 = *(const uint4*)(kbase + (long)(ck + krow) * HD + khalf);
        uint4 kv1 = *(const uint4*)(kbase + (long)(ck + krow) * HD + khalf + 8);
        uint4 vv0 = *(const uint4*)(vbase + (long)vrow * LKV + ck + vkoff);
        uint4 vv1 = *(const uint4*)(vbase + (long)vrow * LKV + ck + vkoff + 8);
        __syncthreads();
        *(uint4*)&sK[krow * 40 + khalf] = kv0;
        *(uint4*)&sK[krow * 40 + khalf + 8] = kv1;
        *(uint4*)&sVT[vrow * 136 + vkoff] = vv0;
        *(uint4*)&sVT[vrow * 136 + vkoff + 8] = vv1;
        __syncthreads();
        // S = Q K^T -> exp -> l partial + P^T to (wave-private) LDS
#pragma unroll
        for (int nf = 0; nf < 8; nf++) {
            short8 bk = *(const short8*)&sK[(nf * 16 + lid) * 40 + quad * 8];
#pragma unroll
            for (int mf = 0; mf < 2; mf++) {
                float4v z = (float4v){0.f, 0.f, 0.f, 0.f};
                float4v s = mfma16(aq[mf], bk, z);
                float e0 = __expf(s[0]), e1 = __expf(s[1]);
                float e2 = __expf(s[2]), e3 = __expf(s[3]);
                l[mf * 4 + 0] += e0; l[mf * 4 + 1] += e1;
                l[mf * 4 + 2] += e2; l[mf * 4 + 3] += e3;
                uint2 pk;
                pk.x = pack2_rtz(e0, e1);
                pk.y = pack2_rtz(e2, e3);
                *(uint2*)&myPT[(nf * 16 + lid) * 36 + mf * 16 + quad * 4] = pk;
            }
        }
        // O += P V   (myPT wave-private: no barrier needed)
#pragma unroll
        for (int kb2 = 0; kb2 < 4; kb2++) {
            short8 bv0 = *(const short8*)&sVT[lid * 136 + kb2 * 32 + quad * 8];
            short8 bv1 = *(const short8*)&sVT[(16 + lid) * 136 + kb2 * 32 + quad * 8];
#pragma unroll
            for (int mf = 0; mf < 2; mf++) {
                short8 ap;
#pragma unroll
                for (int j = 0; j < 8; j++)
                    ap[j] = (short)myPT[(kb2 * 32 + quad * 8 + j) * 36 + mf * 16 + lid];
                o[mf][0] = mfma16(ap, bv0, o[mf][0]);
                o[mf][1] = mfma16(ap, bv1, o[mf][1]);
            }
        }
    }
    // reduce l across the 16 lids (all hold partials of same q rows)
#pragma unroll
    for (int i = 0; i < 8; i++) {
#pragma unroll
        for (int d = 1; d < 16; d <<= 1) l[i] += __shfl_xor(l[i], d);
    }
#pragma unroll
    for (int mf = 0; mf < 2; mf++)
#pragma unroll
        for (int r = 0; r < 4; r++) {
            long orow = ((long)blockIdx.z * 32 + bh) * LQ + qt0 + wave * 32 + mf * 16 + quad * 4 + r;
            Opart[orow * HD + lid] = o[mf][0][r];
            Opart[orow * HD + 16 + lid] = o[mf][1][r];
            if (lid == 0) lpart[orow] = l[mf * 4 + r];
        }
}

// ---------------- combine split-KV partials (plain sums) -> o[lq*B+b][h*32+d] f32 ----------------
__global__ void attn_combine(const float* __restrict__ Opart, const float* __restrict__ lpart,
                             float* __restrict__ o) {
    const int t = threadIdx.x;
    const int r = blockIdx.x * 8 + (t >> 5);   // r = bh*512 + qrow, 16384 total
    const int d = t & 31;
    float L = 0.f, acc = 0.f;
#pragma unroll
    for (int s = 0; s < SPLITS; s++) {
        L += lpart[s * 16384 + r];
        acc += Opart[(long)(s * 16384 + r) * HD + d];
    }
    const int bh = r >> 9, qrow = r & 511;
    const int b = bh >> 3, h = bh & 7;
    o[(long)(qrow * NB + b) * E + h * HD + d] = acc / L;
}

// ---------------- LayerNorm over E=256: block 256 = 4 rows x 64 lanes ----------------
__global__ void ln_k(const float* __restrict__ in, const float* __restrict__ g,
                     const float* __restrict__ b, float* __restrict__ out,
                     float* __restrict__ out2) {
    const int t = threadIdx.x;
    const int lane = t & 63;
    const int row = blockIdx.x * 4 + (t >> 6);
    const float4 v = *(const float4*)&in[(long)row * E + lane * 4];
    float s = v.x + v.y + v.z + v.w;
#pragma unroll
    for (int d = 1; d < 64; d <<= 1) s += __shfl_xor(s, d);
    const float mean = s * (1.f / 256.f);
    float dx0 = v.x - mean, dx1 = v.y - mean, dx2 = v.z - mean, dx3 = v.w - mean;
    float ss = dx0 * dx0 + dx1 * dx1 + dx2 * dx2 + dx3 * dx3;
#pragma unroll
    for (int d = 1; d < 64; d <<= 1) ss += __shfl_xor(ss, d);
    const float rstd = rsqrtf(ss * (1.f / 256.f) + 1e-5f);
    const int c0 = lane * 4;
    float4 gg = *(const float4*)&g[c0];
    float4 bb = *(const float4*)&b[c0];
    float4 ov;
    ov.x = dx0 * rstd * gg.x + bb.x;
    ov.y = dx1 * rstd * gg.y + bb.y;
    ov.z = dx2 * rstd * gg.z + bb.z;
    ov.w = dx3 * rstd * gg.w + bb.w;
    *(float4*)&out[(long)row * E + c0] = ov;
    if (out2) *(float4*)&out2[(long)row * E + c0] = ov;
}

extern "C" void kernel_launch(void* const* d_in, const int* in_sizes, int n_in,
                              void* d_out, int out_size, void* d_ws, size_t ws_size,
                              hipStream_t stream) {
    (void)in_sizes; (void)n_in; (void)out_size; (void)ws_size;
    const float* query = (const float*)d_in[0];
    const float* value = (const float*)d_in[1];
    const float* qpos  = (const float*)d_in[2];
    const float* vpos  = (const float*)d_in[3];
    const float* Wqkv  = (const float*)d_in[4];
    const float* bqkv  = (const float*)d_in[5];
    const float* Wo    = (const float*)d_in[6];
    const float* bo    = (const float*)d_in[7];
    const float* g1    = (const float*)d_in[8];
    const float* be1   = (const float*)d_in[9];
    const float* W1    = (const float*)d_in[10];
    const float* b1    = (const float*)d_in[11];
    const float* W2    = (const float*)d_in[12];
    const float* b2    = (const float*)d_in[13];
    const float* g2    = (const float*)d_in[14];
    const float* be2   = (const float*)d_in[15];
    float* outp = (float*)d_out;

    char* w = (char*)d_ws;
    float*          cur   = (float*)(w + 0);                    // 2 MB  [2048][256] f32
    unsigned short* qbuf  = (unsigned short*)(w + (2l  << 20)); // 1 MB  [B][H][LQ][HD] bf16
    unsigned short* kbuf  = (unsigned short*)(w + (3l  << 20)); // 8 MB  [B][H][LKV][HD] bf16
    unsigned short* vtb   = (unsigned short*)(w + (11l << 20)); // 8 MB  [B][H][HD][LKV] bf16
    float*          obuf  = (float*)(w + (19l << 20));          // 2 MB
    float*          tmp   = (float*)(w + (21l << 20));          // 2 MB
    float*          xb    = (float*)(w + (23l << 20));          // 2 MB
    float*          h1b   = (float*)(w + (25l << 20));          // 2 MB
    float*          Opart = (float*)(w + (27l << 20));          // 8 MB  [S][32][512][32] f32
    float*          lp    = (float*)(w + (35l << 20));          // 64 KB

    init_cur<<<2048, 256, 0, stream>>>(query, cur);
    for (int layer = 0; layer < NLAYER; layer++) {
        const float* Wl = Wqkv + (long)layer * 768 * 256;
        const float* bl = bqkv + (long)layer * 768;
        qkv_q<<<dim3(32, 4), 256, 0, stream>>>(cur, Wl, bl, qpos, qbuf);
        qkv_kv<<<256, 512, 0, stream>>>(value, Wl + 256 * 256, bl + 256, vpos, kbuf, vtb);
        attn_k<<<dim3(LQ / QT, 32, SPLITS), 256, 0, stream>>>(qbuf, kbuf, vtb, Opart, lp);
        attn_combine<<<2048, 256, 0, stream>>>(Opart, lp, obuf);
        gemm_k<<<dim3(64, 4), 256, 0, stream>>>(obuf, Wo + layer * 65536, bo + layer * 256, cur, tmp, 0);
        ln_k<<<512, 256, 0, stream>>>(tmp, g1 + layer * 256, be1 + layer * 256, xb, nullptr);
        gemm_k<<<dim3(64, 4), 256, 0, stream>>>(xb, W1 + layer * 65536, b1 + layer * 256, nullptr, h1b, 1);
        gemm_k<<<dim3(64, 4), 256, 0, stream>>>(h1b, W2 + layer * 65536, b2 + layer * 256, xb, tmp, 0);
        ln_k<<<512, 256, 0, stream>>>(tmp, g2 + layer * 256, be2 + layer * 256, cur,
                                      outp + (long)layer * LQ * NB * E);
    }
}

// Round 4
// 460.641 us; speedup vs baseline: 1.4508x; 1.2253x over previous
//
#include <hip/hip_runtime.h>
#include <hip/hip_bf16.h>

typedef __attribute__((ext_vector_type(8))) short short8;
typedef __attribute__((ext_vector_type(4))) float float4v;
typedef __attribute__((ext_vector_type(4))) unsigned short ushort4v;

#define LQ 512
#define NB 4
#define LKV 4096
#define E 256
#define NH 8
#define HD 32
#define NLAYER 4
#define QSCALE 0.17677669529663687f
#define SPLITS 4
#define KSPAN (LKV / SPLITS)
#define QT 128   // q rows per attn block
#define CK 128   // keys per attn chunk

__device__ __forceinline__ unsigned short f2bf(float f) {
    union { float f; unsigned int i; } x; x.f = f;
    unsigned int r = x.i + 0x7fffu + ((x.i >> 16) & 1u);
    return (unsigned short)(r >> 16);
}
__device__ __forceinline__ unsigned int pack2(float a, float b) {
    return (unsigned int)f2bf(a) | ((unsigned int)f2bf(b) << 16);
}
__device__ __forceinline__ unsigned int pack2_rtz(float a, float b) {
    union { float f; unsigned int i; } xa, xb; xa.f = a; xb.f = b;
    return __builtin_amdgcn_perm(xb.i, xa.i, 0x07060302u);
}
__device__ __forceinline__ float bf2f(unsigned short u) {
    union { unsigned int i; float f; } x; x.i = ((unsigned int)u) << 16; return x.f;
}
__device__ __forceinline__ float4v mfma16(short8 a, short8 b, float4v c) {
    return __builtin_amdgcn_mfma_f32_16x16x32_bf16(a, b, c, 0, 0, 0);
}

// ---------------- pack f32 -> bf16, 8 elems/thread ----------------
__global__ void pack_k(const float* __restrict__ in, unsigned short* __restrict__ out) {
    long i = ((long)blockIdx.x * 256 + threadIdx.x) * 8;
    float4 a = *(const float4*)&in[i];
    float4 b = *(const float4*)&in[i + 4];
    uint4 v;
    v.x = pack2(a.x, a.y); v.y = pack2(a.z, a.w);
    v.z = pack2(b.x, b.y); v.w = pack2(b.z, b.w);
    *(uint4*)&out[i] = v;
}

// ---------------- init: cur = query (f32) + cur_bf ----------------
__global__ void init_cur(const float* __restrict__ q, float* __restrict__ cur,
                         unsigned short* __restrict__ cur_bf) {
    int i = blockIdx.x * 256 + threadIdx.x;
    float v = q[i];
    cur[i] = v;
    cur_bf[i] = f2bf(v);
}

// ---------------- generic GEMM: out = A_bf@W_bf^T + bias (+res f32)(relu) ----------------
// A bf16 [M][256], W bf16 [N][256]. Tile M=32/N=64, full-K LDS, grid (M/32, N/64), 256 thr.
__global__ __launch_bounds__(256) void gemm_k(
        const unsigned short* __restrict__ A, const unsigned short* __restrict__ W,
        const float* __restrict__ bias, const float* __restrict__ res,
        float* __restrict__ out, unsigned short* __restrict__ out_bf, int relu) {
    __shared__ unsigned short sA[32 * 264];
    __shared__ unsigned short sB[64 * 264];
    const int t = threadIdx.x;
    const int lane = t & 63, wave = t >> 6, quad = lane >> 4, lid = lane & 15;
    const int row0 = blockIdx.x * 32, col0 = blockIdx.y * 64;
    {   // stage A: 32 rows x 256 K (32 elems/thread)
        int r = t >> 3, ks = (t & 7) * 32;
        const unsigned short* ap = A + (long)(row0 + r) * E + ks;
#pragma unroll
        for (int i = 0; i < 4; i++)
            *(uint4*)&sA[r * 264 + ks + i * 8] = *(const uint4*)(ap + i * 8);
    }
    {   // stage B: 64 rows x 256 K (64 elems/thread)
        int r = t >> 2, ks = (t & 3) * 64;
        const unsigned short* wp = W + (long)(col0 + r) * E + ks;
#pragma unroll
        for (int i = 0; i < 8; i++)
            *(uint4*)&sB[r * 264 + ks + i * 8] = *(const uint4*)(wp + i * 8);
    }
    __syncthreads();
    float4v acc[2];
    acc[0] = (float4v){0.f, 0.f, 0.f, 0.f};
    acc[1] = (float4v){0.f, 0.f, 0.f, 0.f};
#pragma unroll
    for (int k0 = 0; k0 < E; k0 += 32) {
        short8 bf = *(const short8*)&sB[(wave * 16 + lid) * 264 + k0 + quad * 8];
        short8 af0 = *(const short8*)&sA[(lid) * 264 + k0 + quad * 8];
        short8 af1 = *(const short8*)&sA[(16 + lid) * 264 + k0 + quad * 8];
        acc[0] = mfma16(af0, bf, acc[0]);
        acc[1] = mfma16(af1, bf, acc[1]);
    }
#pragma unroll
    for (int mt = 0; mt < 2; mt++)
#pragma unroll
        for (int r = 0; r < 4; r++) {
            int grow = row0 + mt * 16 + quad * 4 + r;
            int gcol = col0 + wave * 16 + lid;
            float v = acc[mt][r] + bias[gcol];
            if (res) v += res[(long)grow * E + gcol];
            if (relu) v = fmaxf(v, 0.f);
            if (out) out[(long)grow * E + gcol] = v;
            if (out_bf) out_bf[(long)grow * E + gcol] = f2bf(v);
        }
}

// ---------------- Q projection + scale + rotary -> qbuf[b][h][lq][hd] bf16 ----------------
// A = cur_bf [2048][256], W = wq_bf [256][256]. Tile 32x64, grid (64,4), 256 thr.
__global__ __launch_bounds__(256) void qkv_q(
        const unsigned short* __restrict__ A, const unsigned short* __restrict__ W,
        const float* __restrict__ bias, const unsigned short* __restrict__ pos,
        unsigned short* __restrict__ qout) {
    __shared__ unsigned short sA[32 * 40];
    __shared__ unsigned short sB[64 * 40];
    const int t = threadIdx.x;
    const int lane = t & 63, wave = t >> 6, quad = lane >> 4, lid = lane & 15;
    const int row0 = blockIdx.x * 32, col0 = blockIdx.y * 64;
    const int sr = t >> 2, sk = (t & 3) * 8;
    const unsigned short* ap = A + (long)(row0 + sr) * E + sk;   // valid t<128
    const unsigned short* wp = W + (long)(col0 + sr) * E + sk;
    uint4 av, bv;
    if (t < 128) av = *(const uint4*)ap;
    bv = *(const uint4*)wp;
    float4v acc[2];
    acc[0] = (float4v){0.f, 0.f, 0.f, 0.f};
    acc[1] = (float4v){0.f, 0.f, 0.f, 0.f};
#pragma unroll
    for (int ki = 0; ki < 8; ki++) {
        __syncthreads();
        if (t < 128) *(uint4*)&sA[sr * 40 + sk] = av;
        *(uint4*)&sB[sr * 40 + sk] = bv;
        __syncthreads();
        if (ki < 7) {
            if (t < 128) av = *(const uint4*)(ap + (ki + 1) * 32);
            bv = *(const uint4*)(wp + (ki + 1) * 32);
        }
        short8 af0 = *(const short8*)&sA[lid * 40 + quad * 8];
        short8 af1 = *(const short8*)&sA[(16 + lid) * 40 + quad * 8];
        short8 bf = *(const short8*)&sB[(wave * 16 + lid) * 40 + quad * 8];
        acc[0] = mfma16(af0, bf, acc[0]);
        acc[1] = mfma16(af1, bf, acc[1]);
    }
#pragma unroll
    for (int mt = 0; mt < 2; mt++)
#pragma unroll
        for (int r = 0; r < 4; r++) {
            int grow = row0 + mt * 16 + quad * 4 + r;
            int gcol = col0 + wave * 16 + lid;
            float v = (acc[mt][r] + bias[gcol]) * QSCALE;
            int seq = grow >> 2, b = grow & 3;
            int c = gcol;
            unsigned int cs = *(const unsigned int*)&pos[(((long)b * LQ + seq) * E + c) * 2];
            float cv = bf2f((unsigned short)cs), sv = bf2f((unsigned short)(cs >> 16));
            float p = __shfl_xor(v, 1);
            float x2 = (c & 1) ? p : -p;
            float rv = v * cv + x2 * sv;
            qout[(((long)b * NH + (c >> 5)) * LQ + seq) * HD + (c & 31)] = f2bf(rv);
        }
}

// ---------------- KV projection: A=value_bf, W=wkv_bf [512][256] ----------------
// Tile 64x64, grid (256, 8), 256 thr = 4 waves 2x2. Rotary K / transpose V epilogue.
__global__ __launch_bounds__(256) void qkv_kv(
        const unsigned short* __restrict__ A, const unsigned short* __restrict__ W,
        const float* __restrict__ bias, const unsigned short* __restrict__ pos,
        unsigned short* __restrict__ kout, unsigned short* __restrict__ vtout) {
    __shared__ unsigned short sA[64 * 40];
    __shared__ unsigned short sB[64 * 40];
    const int t = threadIdx.x;
    const int lane = t & 63, wave = t >> 6, quad = lane >> 4, lid = lane & 15;
    const int wr = wave >> 1, wc = wave & 1;
    const int row0 = blockIdx.x * 64, col0 = blockIdx.y * 64;
    const int sr = t >> 2, sk = (t & 3) * 8;
    const unsigned short* ap = A + (long)(row0 + sr) * E + sk;
    const unsigned short* wp = W + (long)(col0 + sr) * E + sk;
    uint4 av = *(const uint4*)ap;
    uint4 bv = *(const uint4*)wp;
    float4v acc[2][2];
    for (int i = 0; i < 2; i++) for (int j = 0; j < 2; j++) acc[i][j] = (float4v){0.f, 0.f, 0.f, 0.f};
#pragma unroll
    for (int ki = 0; ki < 8; ki++) {
        __syncthreads();
        *(uint4*)&sA[sr * 40 + sk] = av;
        *(uint4*)&sB[sr * 40 + sk] = bv;
        __syncthreads();
        if (ki < 7) {
            av = *(const uint4*)(ap + (ki + 1) * 32);
            bv = *(const uint4*)(wp + (ki + 1) * 32);
        }
        short8 af0 = *(const short8*)&sA[(wr * 32 + lid) * 40 + quad * 8];
        short8 af1 = *(const short8*)&sA[(wr * 32 + 16 + lid) * 40 + quad * 8];
        short8 bf0 = *(const short8*)&sB[(wc * 32 + lid) * 40 + quad * 8];
        short8 bf1 = *(const short8*)&sB[(wc * 32 + 16 + lid) * 40 + quad * 8];
        acc[0][0] = mfma16(af0, bf0, acc[0][0]);
        acc[0][1] = mfma16(af0, bf1, acc[0][1]);
        acc[1][0] = mfma16(af1, bf0, acc[1][0]);
        acc[1][1] = mfma16(af1, bf1, acc[1][1]);
    }
#pragma unroll
    for (int mt = 0; mt < 2; mt++)
#pragma unroll
        for (int nt = 0; nt < 2; nt++)
#pragma unroll
            for (int r = 0; r < 4; r++) {
                int grow = row0 + wr * 32 + mt * 16 + quad * 4 + r;
                int gcol = col0 + wc * 32 + nt * 16 + lid;
                float v = acc[mt][nt][r] + bias[gcol];
                int seq = grow >> 2, b = grow & 3;
                if (gcol < E) {  // K half: rotary (wave-uniform at 16-col granularity, boundary 256)
                    int c = gcol;
                    unsigned int cs = *(const unsigned int*)&pos[(((long)b * LKV + seq) * E + c) * 2];
                    float cv = bf2f((unsigned short)cs), sv = bf2f((unsigned short)(cs >> 16));
                    float p = __shfl_xor(v, 1);
                    float x2 = (c & 1) ? p : -p;
                    float rv = v * cv + x2 * sv;
                    kout[(((long)b * NH + (c >> 5)) * LKV + seq) * HD + (c & 31)] = f2bf(rv);
                } else {         // V half: store transposed
                    int c = gcol - E;
                    vtout[(((long)b * NH + (c >> 5)) * HD + (c & 31)) * (long)LKV + seq] = f2bf(v);
                }
            }
}

// ---------------- flash attention, split-KV, no online max (scores bounded) ----------------
__global__ __launch_bounds__(256) void attn_k(
        const unsigned short* __restrict__ qb, const unsigned short* __restrict__ kb,
        const unsigned short* __restrict__ vtb, float* __restrict__ Opart,
        float* __restrict__ lpart) {
    __shared__ unsigned short sK[CK * 40];
    __shared__ unsigned short sVT[32 * 136];
    __shared__ unsigned short sPT[4 * CK * 36];
    const int t = threadIdx.x;
    const int lane = t & 63, wave = t >> 6, quad = lane >> 4, lid = lane & 15;
    const int qt0 = blockIdx.x * QT;
    const int bh = blockIdx.y;
    const int key0 = blockIdx.z * KSPAN;
    const unsigned short* kbase = kb + (long)bh * LKV * HD;
    const unsigned short* vbase = vtb + (long)bh * HD * LKV;
    short8 aq[2];
#pragma unroll
    for (int mf = 0; mf < 2; mf++)
        aq[mf] = *(const short8*)(qb + ((long)bh * LQ + qt0 + wave * 32 + mf * 16 + lid) * HD + quad * 8);
    float4v o[2][2];
#pragma unroll
    for (int i = 0; i < 2; i++) for (int j = 0; j < 2; j++) o[i][j] = (float4v){0.f, 0.f, 0.f, 0.f};
    float l[8] = {0.f, 0.f, 0.f, 0.f, 0.f, 0.f, 0.f, 0.f};
    const int krow = t >> 1, khalf = (t & 1) * 16;
    const int vrow = t >> 3, vkoff = (t & 7) * 16;
    unsigned short* myPT = &sPT[wave * CK * 36];
    for (int ck = key0; ck < key0 + KSPAN; ck += CK) {
        uint4 kv0 = *(const uint4*)(kbase + (long)(ck + krow) * HD + khalf);
        uint4 kv1 = *(const uint4*)(kbase + (long)(ck + krow) * HD + khalf + 8);
        uint4 vv0 = *(const uint4*)(vbase + (long)vrow * LKV + ck + vkoff);
        uint4 vv1 = *(const uint4*)(vbase + (long)vrow * LKV + ck + vkoff + 8);
        __syncthreads();
        *(uint4*)&sK[krow * 40 + khalf] = kv0;
        *(uint4*)&sK[krow * 40 + khalf + 8] = kv1;
        *(uint4*)&sVT[vrow * 136 + vkoff] = vv0;
        *(uint4*)&sVT[vrow * 136 + vkoff + 8] = vv1;
        __syncthreads();
#pragma unroll
        for (int nf = 0; nf < 8; nf++) {
            short8 bk = *(const short8*)&sK[(nf * 16 + lid) * 40 + quad * 8];
#pragma unroll
            for (int mf = 0; mf < 2; mf++) {
                float4v z = (float4v){0.f, 0.f, 0.f, 0.f};
                float4v s = mfma16(aq[mf], bk, z);
                float e0 = __expf(s[0]), e1 = __expf(s[1]);
                float e2 = __expf(s[2]), e3 = __expf(s[3]);
                l[mf * 4 + 0] += e0; l[mf * 4 + 1] += e1;
                l[mf * 4 + 2] += e2; l[mf * 4 + 3] += e3;
                uint2 pk;
                pk.x = pack2_rtz(e0, e1);
                pk.y = pack2_rtz(e2, e3);
                *(uint2*)&myPT[(nf * 16 + lid) * 36 + mf * 16 + quad * 4] = pk;
            }
        }
#pragma unroll
        for (int kb2 = 0; kb2 < 4; kb2++) {
            short8 bv0 = *(const short8*)&sVT[lid * 136 + kb2 * 32 + quad * 8];
            short8 bv1 = *(const short8*)&sVT[(16 + lid) * 136 + kb2 * 32 + quad * 8];
#pragma unroll
            for (int mf = 0; mf < 2; mf++) {
                short8 ap;
#pragma unroll
                for (int j = 0; j < 8; j++)
                    ap[j] = (short)myPT[(kb2 * 32 + quad * 8 + j) * 36 + mf * 16 + lid];
                o[mf][0] = mfma16(ap, bv0, o[mf][0]);
                o[mf][1] = mfma16(ap, bv1, o[mf][1]);
            }
        }
    }
#pragma unroll
    for (int i = 0; i < 8; i++) {
#pragma unroll
        for (int d = 1; d < 16; d <<= 1) l[i] += __shfl_xor(l[i], d);
    }
#pragma unroll
    for (int mf = 0; mf < 2; mf++)
#pragma unroll
        for (int r = 0; r < 4; r++) {
            long orow = ((long)blockIdx.z * 32 + bh) * LQ + qt0 + wave * 32 + mf * 16 + quad * 4 + r;
            Opart[orow * HD + lid] = o[mf][0][r];
            Opart[orow * HD + 16 + lid] = o[mf][1][r];
            if (lid == 0) lpart[orow] = l[mf * 4 + r];
        }
}

// ---------------- combine split-KV partials -> obuf_bf [lq*B+b][h*32+d] bf16 ----------------
__global__ void attn_combine(const float* __restrict__ Opart, const float* __restrict__ lpart,
                             unsigned short* __restrict__ o_bf) {
    const int t = threadIdx.x;
    const int r = blockIdx.x * 8 + (t >> 5);
    const int d = t & 31;
    float L = 0.f, acc = 0.f;
#pragma unroll
    for (int s = 0; s < SPLITS; s++) {
        L += lpart[s * 16384 + r];
        acc += Opart[(long)(s * 16384 + r) * HD + d];
    }
    const int bh = r >> 9, qrow = r & 511;
    const int b = bh >> 3, h = bh & 7;
    o_bf[(long)(qrow * NB + b) * E + h * HD + d] = f2bf(acc / L);
}

// ---------------- LayerNorm over E=256: block 256 = 4 rows x 64 lanes ----------------
__global__ void ln_k(const float* __restrict__ in, const float* __restrict__ g,
                     const float* __restrict__ b, float* __restrict__ out,
                     float* __restrict__ out2, unsigned short* __restrict__ out_bf) {
    const int t = threadIdx.x;
    const int lane = t & 63;
    const int row = blockIdx.x * 4 + (t >> 6);
    const float4 v = *(const float4*)&in[(long)row * E + lane * 4];
    float s = v.x + v.y + v.z + v.w;
#pragma unroll
    for (int d = 1; d < 64; d <<= 1) s += __shfl_xor(s, d);
    const float mean = s * (1.f / 256.f);
    float dx0 = v.x - mean, dx1 = v.y - mean, dx2 = v.z - mean, dx3 = v.w - mean;
    float ss = dx0 * dx0 + dx1 * dx1 + dx2 * dx2 + dx3 * dx3;
#pragma unroll
    for (int d = 1; d < 64; d <<= 1) ss += __shfl_xor(ss, d);
    const float rstd = rsqrtf(ss * (1.f / 256.f) + 1e-5f);
    const int c0 = lane * 4;
    float4 gg = *(const float4*)&g[c0];
    float4 bb = *(const float4*)&b[c0];
    float4 ov;
    ov.x = dx0 * rstd * gg.x + bb.x;
    ov.y = dx1 * rstd * gg.y + bb.y;
    ov.z = dx2 * rstd * gg.z + bb.z;
    ov.w = dx3 * rstd * gg.w + bb.w;
    *(float4*)&out[(long)row * E + c0] = ov;
    if (out2) *(float4*)&out2[(long)row * E + c0] = ov;
    if (out_bf) {
        uint2 u; u.x = pack2(ov.x, ov.y); u.y = pack2(ov.z, ov.w);
        *(uint2*)&out_bf[(long)row * E + c0] = u;
    }
}

extern "C" void kernel_launch(void* const* d_in, const int* in_sizes, int n_in,
                              void* d_out, int out_size, void* d_ws, size_t ws_size,
                              hipStream_t stream) {
    (void)in_sizes; (void)n_in; (void)out_size; (void)ws_size;
    const float* query = (const float*)d_in[0];
    const float* value = (const float*)d_in[1];
    const float* qpos  = (const float*)d_in[2];
    const float* vpos  = (const float*)d_in[3];
    const float* Wqkv  = (const float*)d_in[4];
    const float* bqkv  = (const float*)d_in[5];
    const float* Wo    = (const float*)d_in[6];
    const float* bo    = (const float*)d_in[7];
    const float* g1    = (const float*)d_in[8];
    const float* be1   = (const float*)d_in[9];
    const float* W1    = (const float*)d_in[10];
    const float* b1    = (const float*)d_in[11];
    const float* W2    = (const float*)d_in[12];
    const float* b2    = (const float*)d_in[13];
    const float* g2    = (const float*)d_in[14];
    const float* be2   = (const float*)d_in[15];
    float* outp = (float*)d_out;

    char* w = (char*)d_ws;
    float*          cur     = (float*)(w + 0);                    // 2 MB  [2048][256] f32
    unsigned short* cur_bf  = (unsigned short*)(w + (2l  << 20)); // 1 MB
    unsigned short* qbuf    = (unsigned short*)(w + (3l  << 20)); // 1 MB  [B][H][LQ][HD]
    unsigned short* kbuf    = (unsigned short*)(w + (4l  << 20)); // 8 MB  [B][H][LKV][HD]
    unsigned short* vtb     = (unsigned short*)(w + (12l << 20)); // 8 MB  [B][H][HD][LKV]
    unsigned short* obuf_bf = (unsigned short*)(w + (20l << 20)); // 1 MB
    float*          tmp     = (float*)(w + (21l << 20));          // 2 MB
    float*          xb      = (float*)(w + (23l << 20));          // 2 MB
    unsigned short* xb_bf   = (unsigned short*)(w + (25l << 20)); // 1 MB
    unsigned short* h1b_bf  = (unsigned short*)(w + (26l << 20)); // 1 MB
    float*          Opart   = (float*)(w + (27l << 20));          // 8 MB
    float*          lp      = (float*)(w + (35l << 20));          // 64 KB
    unsigned short* val_bf  = (unsigned short*)(w + (36l << 20)); // 8 MB  [16384][256]
    unsigned short* wqkv_bf = (unsigned short*)(w + (44l << 20)); // 1.5 MB [4][768][256]
    unsigned short* wo_bf   = (unsigned short*)(w + (46l << 20)); // 0.5 MB
    unsigned short* w1_bf   = (unsigned short*)(w + (47l << 20)); // 0.5 MB
    unsigned short* w2_bf   = (unsigned short*)(w + (48l << 20)); // 0.5 MB
    unsigned short* qpos_bf = (unsigned short*)(w + (49l << 20)); // 2 MB
    unsigned short* vpos_bf = (unsigned short*)(w + (51l << 20)); // 16 MB

    init_cur<<<2048, 256, 0, stream>>>(query, cur, cur_bf);
    pack_k<<<2048, 256, 0, stream>>>(value, val_bf);    // 4.19M elems
    pack_k<<<384,  256, 0, stream>>>(Wqkv, wqkv_bf);    // 786432
    pack_k<<<128,  256, 0, stream>>>(Wo, wo_bf);        // 262144
    pack_k<<<128,  256, 0, stream>>>(W1, w1_bf);
    pack_k<<<128,  256, 0, stream>>>(W2, w2_bf);
    pack_k<<<512,  256, 0, stream>>>(qpos, qpos_bf);    // 1048576
    pack_k<<<4096, 256, 0, stream>>>(vpos, vpos_bf);    // 8388608

    for (int layer = 0; layer < NLAYER; layer++) {
        const unsigned short* Wl = wqkv_bf + (long)layer * 768 * 256;
        const float* bl = bqkv + (long)layer * 768;
        qkv_q<<<dim3(64, 4), 256, 0, stream>>>(cur_bf, Wl, bl, qpos_bf, qbuf);
        qkv_kv<<<dim3(256, 8), 256, 0, stream>>>(val_bf, Wl + 256 * 256, bl + 256, vpos_bf, kbuf, vtb);
        attn_k<<<dim3(LQ / QT, 32, SPLITS), 256, 0, stream>>>(qbuf, kbuf, vtb, Opart, lp);
        attn_combine<<<2048, 256, 0, stream>>>(Opart, lp, obuf_bf);
        gemm_k<<<dim3(64, 4), 256, 0, stream>>>(obuf_bf, wo_bf + layer * 65536, bo + layer * 256,
                                                cur, tmp, nullptr, 0);
        ln_k<<<512, 256, 0, stream>>>(tmp, g1 + layer * 256, be1 + layer * 256, xb, nullptr, xb_bf);
        gemm_k<<<dim3(64, 4), 256, 0, stream>>>(xb_bf, w1_bf + layer * 65536, b1 + layer * 256,
                                                nullptr, nullptr, h1b_bf, 1);
        gemm_k<<<dim3(64, 4), 256, 0, stream>>>(h1b_bf, w2_bf + layer * 65536, b2 + layer * 256,
                                                xb, tmp, nullptr, 0);
        ln_k<<<512, 256, 0, stream>>>(tmp, g2 + layer * 256, be2 + layer * 256, cur,
                                      outp + (long)layer * LQ * NB * E, cur_bf);
    }
}

// Round 5
// 435.232 us; speedup vs baseline: 1.5355x; 1.0584x over previous
//
#include <hip/hip_runtime.h>
#include <hip/hip_bf16.h>

typedef __attribute__((ext_vector_type(8))) short short8;
typedef __attribute__((ext_vector_type(4))) float float4v;
typedef __attribute__((ext_vector_type(4))) unsigned short ushort4v;

#define LQ 512
#define NB 4
#define LKV 4096
#define E 256
#define NH 8
#define HD 32
#define NLAYER 4
#define QSCALE 0.17677669529663687f
#define SPLITS 4
#define KSPAN (LKV / SPLITS)
#define QT 128   // q rows per attn block
#define CK 128   // keys per attn chunk

__device__ __forceinline__ unsigned short f2bf(float f) {
    union { float f; unsigned int i; } x; x.f = f;
    unsigned int r = x.i + 0x7fffu + ((x.i >> 16) & 1u);
    return (unsigned short)(r >> 16);
}
__device__ __forceinline__ unsigned int pack2(float a, float b) {
    union { float f; unsigned int i; } xa, xb; xa.f = a; xb.f = b;
    unsigned int ra = xa.i + 0x7fffu + ((xa.i >> 16) & 1u);
    unsigned int rb = xb.i + 0x7fffu + ((xb.i >> 16) & 1u);
    return (ra >> 16) | (rb & 0xffff0000u);
}
__device__ __forceinline__ unsigned int pack2_rtz(float a, float b) {
    union { float f; unsigned int i; } xa, xb; xa.f = a; xb.f = b;
    return __builtin_amdgcn_perm(xb.i, xa.i, 0x07060302u);
}
__device__ __forceinline__ float bf2f(unsigned short u) {
    union { unsigned int i; float f; } x; x.i = ((unsigned int)u) << 16; return x.f;
}
__device__ __forceinline__ float4v mfma16(short8 a, short8 b, float4v c) {
    return __builtin_amdgcn_mfma_f32_16x16x32_bf16(a, b, c, 0, 0, 0);
}

// ---------------- pack f32 -> bf16, 8 elems/thread ----------------
__global__ void pack_k(const float* __restrict__ in, unsigned short* __restrict__ out) {
    long i = ((long)blockIdx.x * 256 + threadIdx.x) * 8;
    float4 a = *(const float4*)&in[i];
    float4 b = *(const float4*)&in[i + 4];
    uint4 v;
    v.x = pack2(a.x, a.y); v.y = pack2(a.z, a.w);
    v.z = pack2(b.x, b.y); v.w = pack2(b.z, b.w);
    *(uint4*)&out[i] = v;
}

// ---------------- init: cur = query (f32) + cur_bf ----------------
__global__ void init_cur(const float* __restrict__ q, float* __restrict__ cur,
                         unsigned short* __restrict__ cur_bf) {
    int i = blockIdx.x * 256 + threadIdx.x;
    float v = q[i];
    cur[i] = v;
    cur_bf[i] = f2bf(v);
}

// ---------------- GEMM (W1/relu): out_bf = relu(A_bf@W_bf^T + bias) ----------------
__global__ __launch_bounds__(256) void gemm_k(
        const unsigned short* __restrict__ A, const unsigned short* __restrict__ W,
        const float* __restrict__ bias, unsigned short* __restrict__ out_bf) {
    __shared__ unsigned short sA[32 * 264];
    __shared__ unsigned short sB[64 * 264];
    const int t = threadIdx.x;
    const int lane = t & 63, wave = t >> 6, quad = lane >> 4, lid = lane & 15;
    const int row0 = blockIdx.x * 32, col0 = blockIdx.y * 64;
    {
        int r = t >> 3, ks = (t & 7) * 32;
        const unsigned short* ap = A + (long)(row0 + r) * E + ks;
#pragma unroll
        for (int i = 0; i < 4; i++)
            *(uint4*)&sA[r * 264 + ks + i * 8] = *(const uint4*)(ap + i * 8);
    }
    {
        int r = t >> 2, ks = (t & 3) * 64;
        const unsigned short* wp = W + (long)(col0 + r) * E + ks;
#pragma unroll
        for (int i = 0; i < 8; i++)
            *(uint4*)&sB[r * 264 + ks + i * 8] = *(const uint4*)(wp + i * 8);
    }
    __syncthreads();
    float4v acc[2];
    acc[0] = (float4v){0.f, 0.f, 0.f, 0.f};
    acc[1] = (float4v){0.f, 0.f, 0.f, 0.f};
#pragma unroll
    for (int k0 = 0; k0 < E; k0 += 32) {
        short8 bf = *(const short8*)&sB[(wave * 16 + lid) * 264 + k0 + quad * 8];
        short8 af0 = *(const short8*)&sA[(lid) * 264 + k0 + quad * 8];
        short8 af1 = *(const short8*)&sA[(16 + lid) * 264 + k0 + quad * 8];
        acc[0] = mfma16(af0, bf, acc[0]);
        acc[1] = mfma16(af1, bf, acc[1]);
    }
#pragma unroll
    for (int mt = 0; mt < 2; mt++)
#pragma unroll
        for (int r = 0; r < 4; r++) {
            int grow = row0 + mt * 16 + quad * 4 + r;
            int gcol = col0 + wave * 16 + lid;
            float v = fmaxf(acc[mt][r] + bias[gcol], 0.f);
            out_bf[(long)grow * E + gcol] = f2bf(v);
        }
}

// ---------------- fused GEMM + bias + residual + LayerNorm ----------------
// M=16 rows/block (grid 128), N=256 across 4 waves x 4 nfrags. W streamed from L2.
// COMBINE=1: A rows built from split-KV partials (Opart/lp). OUT2: extra f32 copy (layer out).
template <int COMBINE, int OUT2>
__global__ __launch_bounds__(256) void gemm_ln(
        const unsigned short* __restrict__ A,
        const float* __restrict__ Opart, const float* __restrict__ lp,
        const unsigned short* __restrict__ W, const float* __restrict__ bias,
        const float* __restrict__ res, const float* __restrict__ g,
        const float* __restrict__ bvec, float* __restrict__ outf,
        unsigned short* __restrict__ out_bf, float* __restrict__ outf2) {
    __shared__ unsigned short sA[16 * 264];
    __shared__ float lnS[4][16];
    __shared__ float lnQ[4][16];
    const int t = threadIdx.x;
    const int lane = t & 63, wave = t >> 6, quad = lane >> 4, lid = lane & 15;
    const int row0 = blockIdx.x * 16;
    {   // stage A tile: 16 rows x 256 cols bf16 (16 threads/row, 16 cols each)
        const int r = t >> 4, cseg = t & 15;
        if (COMBINE) {
            const int grow = row0 + r;
            const int seq = grow >> 2, b = grow & 3;
            const int h = cseg >> 1, dd = (cseg & 1) * 16;
            const int bh = b * 8 + h;
            float L = 0.f;
            float av[16];
#pragma unroll
            for (int j = 0; j < 16; j++) av[j] = 0.f;
#pragma unroll
            for (int s = 0; s < SPLITS; s++) {
                long rbase = (long)(s * 32 + bh) * 512 + seq;
                L += lp[rbase];
#pragma unroll
                for (int jj = 0; jj < 4; jj++) {
                    float4 p = *(const float4*)&Opart[rbase * 32 + dd + jj * 4];
                    av[jj * 4 + 0] += p.x; av[jj * 4 + 1] += p.y;
                    av[jj * 4 + 2] += p.z; av[jj * 4 + 3] += p.w;
                }
            }
            float inv = 1.f / L;
            uint4 u0, u1;
            u0.x = pack2(av[0] * inv, av[1] * inv);   u0.y = pack2(av[2] * inv, av[3] * inv);
            u0.z = pack2(av[4] * inv, av[5] * inv);   u0.w = pack2(av[6] * inv, av[7] * inv);
            u1.x = pack2(av[8] * inv, av[9] * inv);   u1.y = pack2(av[10] * inv, av[11] * inv);
            u1.z = pack2(av[12] * inv, av[13] * inv); u1.w = pack2(av[14] * inv, av[15] * inv);
            *(uint4*)&sA[r * 264 + cseg * 16] = u0;
            *(uint4*)&sA[r * 264 + cseg * 16 + 8] = u1;
        } else {
            const unsigned short* ap = A + (long)(row0 + r) * E + cseg * 16;
            *(uint4*)&sA[r * 264 + cseg * 16] = *(const uint4*)ap;
            *(uint4*)&sA[r * 264 + cseg * 16 + 8] = *(const uint4*)(ap + 8);
        }
    }
    __syncthreads();
    float4v acc[4];
#pragma unroll
    for (int nf = 0; nf < 4; nf++) acc[nf] = (float4v){0.f, 0.f, 0.f, 0.f};
#pragma unroll
    for (int k0 = 0; k0 < E; k0 += 32) {
        short8 af = *(const short8*)&sA[lid * 264 + k0 + quad * 8];
#pragma unroll
        for (int nf = 0; nf < 4; nf++) {
            short8 bf = *(const short8*)(W + (long)(wave * 64 + nf * 16 + lid) * E + k0 + quad * 8);
            acc[nf] = mfma16(af, bf, acc[nf]);
        }
    }
    // v = acc + bias + res; per-row sum/sumsq
    float v[4][4];
    float sr[4], qr_[4];
#pragma unroll
    for (int r = 0; r < 4; r++) { sr[r] = 0.f; qr_[r] = 0.f; }
#pragma unroll
    for (int nf = 0; nf < 4; nf++) {
        int col = wave * 64 + nf * 16 + lid;
        float bcol = bias[col];
#pragma unroll
        for (int r = 0; r < 4; r++) {
            int grow = row0 + quad * 4 + r;
            float val = acc[nf][r] + bcol + res[(long)grow * E + col];
            v[nf][r] = val;
            sr[r] += val;
            qr_[r] += val * val;
        }
    }
#pragma unroll
    for (int r = 0; r < 4; r++) {
#pragma unroll
        for (int d = 1; d < 16; d <<= 1) {
            sr[r] += __shfl_xor(sr[r], d);
            qr_[r] += __shfl_xor(qr_[r], d);
        }
    }
    if (lid == 0) {
#pragma unroll
        for (int r = 0; r < 4; r++) {
            lnS[wave][quad * 4 + r] = sr[r];
            lnQ[wave][quad * 4 + r] = qr_[r];
        }
    }
    __syncthreads();
    float mean[4], rstd[4];
#pragma unroll
    for (int r = 0; r < 4; r++) {
        int row = quad * 4 + r;
        float S = lnS[0][row] + lnS[1][row] + lnS[2][row] + lnS[3][row];
        float Q = lnQ[0][row] + lnQ[1][row] + lnQ[2][row] + lnQ[3][row];
        float mu = S * (1.f / 256.f);
        float var = Q * (1.f / 256.f) - mu * mu;
        mean[r] = mu;
        rstd[r] = rsqrtf(var + 1e-5f);
    }
#pragma unroll
    for (int nf = 0; nf < 4; nf++) {
        int col = wave * 64 + nf * 16 + lid;
        float gc = g[col], bc = bvec[col];
#pragma unroll
        for (int r = 0; r < 4; r++) {
            int grow = row0 + quad * 4 + r;
            float xo = (v[nf][r] - mean[r]) * rstd[r] * gc + bc;
            outf[(long)grow * E + col] = xo;
            out_bf[(long)grow * E + col] = f2bf(xo);
            if (OUT2) outf2[(long)grow * E + col] = xo;
        }
    }
}

// ---------------- Q projection + scale + rotary -> qbuf[b][h][lq][hd] bf16 ----------------
__global__ __launch_bounds__(256) void qkv_q(
        const unsigned short* __restrict__ A, const unsigned short* __restrict__ W,
        const float* __restrict__ bias, const unsigned short* __restrict__ pos,
        unsigned short* __restrict__ qout) {
    __shared__ unsigned short sA[32 * 40];
    __shared__ unsigned short sB[64 * 40];
    const int t = threadIdx.x;
    const int lane = t & 63, wave = t >> 6, quad = lane >> 4, lid = lane & 15;
    const int row0 = blockIdx.x * 32, col0 = blockIdx.y * 64;
    const int sr = t >> 2, sk = (t & 3) * 8;
    const unsigned short* ap = A + (long)(row0 + sr) * E + sk;
    const unsigned short* wp = W + (long)(col0 + sr) * E + sk;
    uint4 av, bv;
    if (t < 128) av = *(const uint4*)ap;
    bv = *(const uint4*)wp;
    float4v acc[2];
    acc[0] = (float4v){0.f, 0.f, 0.f, 0.f};
    acc[1] = (float4v){0.f, 0.f, 0.f, 0.f};
#pragma unroll
    for (int ki = 0; ki < 8; ki++) {
        __syncthreads();
        if (t < 128) *(uint4*)&sA[sr * 40 + sk] = av;
        *(uint4*)&sB[sr * 40 + sk] = bv;
        __syncthreads();
        if (ki < 7) {
            if (t < 128) av = *(const uint4*)(ap + (ki + 1) * 32);
            bv = *(const uint4*)(wp + (ki + 1) * 32);
        }
        short8 af0 = *(const short8*)&sA[lid * 40 + quad * 8];
        short8 af1 = *(const short8*)&sA[(16 + lid) * 40 + quad * 8];
        short8 bf = *(const short8*)&sB[(wave * 16 + lid) * 40 + quad * 8];
        acc[0] = mfma16(af0, bf, acc[0]);
        acc[1] = mfma16(af1, bf, acc[1]);
    }
#pragma unroll
    for (int mt = 0; mt < 2; mt++)
#pragma unroll
        for (int r = 0; r < 4; r++) {
            int grow = row0 + mt * 16 + quad * 4 + r;
            int gcol = col0 + wave * 16 + lid;
            float v = (acc[mt][r] + bias[gcol]) * QSCALE;
            int seq = grow >> 2, b = grow & 3;
            int c = gcol;
            unsigned int cs = *(const unsigned int*)&pos[(((long)b * LQ + seq) * E + c) * 2];
            float cv = bf2f((unsigned short)cs), sv = bf2f((unsigned short)(cs >> 16));
            float p = __shfl_xor(v, 1);
            float x2 = (c & 1) ? p : -p;
            float rv = v * cv + x2 * sv;
            qout[(((long)b * NH + (c >> 5)) * LQ + seq) * HD + (c & 31)] = f2bf(rv);
        }
}

// ---------------- KV projection (all layers via blockIdx.z) ----------------
__global__ __launch_bounds__(256) void qkv_kv(
        const unsigned short* __restrict__ A, const unsigned short* __restrict__ Wall,
        const float* __restrict__ ball, const unsigned short* __restrict__ pos,
        unsigned short* __restrict__ kall, unsigned short* __restrict__ vtall) {
    const int layer = blockIdx.z;
    const unsigned short* W = Wall + (long)layer * 768 * 256 + 256 * 256;
    const float* bias = ball + (long)layer * 768 + 256;
    unsigned short* kout = kall + (long)layer * 4194304;
    unsigned short* vtout = vtall + (long)layer * 4194304;
    __shared__ unsigned short sA[64 * 40];
    __shared__ unsigned short sB[64 * 40];
    const int t = threadIdx.x;
    const int lane = t & 63, wave = t >> 6, quad = lane >> 4, lid = lane & 15;
    const int wr = wave >> 1, wc = wave & 1;
    const int row0 = blockIdx.x * 64, col0 = blockIdx.y * 64;
    const int sr = t >> 2, sk = (t & 3) * 8;
    const unsigned short* ap = A + (long)(row0 + sr) * E + sk;
    const unsigned short* wp = W + (long)(col0 + sr) * E + sk;
    uint4 av = *(const uint4*)ap;
    uint4 bv = *(const uint4*)wp;
    float4v acc[2][2];
    for (int i = 0; i < 2; i++) for (int j = 0; j < 2; j++) acc[i][j] = (float4v){0.f, 0.f, 0.f, 0.f};
#pragma unroll
    for (int ki = 0; ki < 8; ki++) {
        __syncthreads();
        *(uint4*)&sA[sr * 40 + sk] = av;
        *(uint4*)&sB[sr * 40 + sk] = bv;
        __syncthreads();
        if (ki < 7) {
            av = *(const uint4*)(ap + (ki + 1) * 32);
            bv = *(const uint4*)(wp + (ki + 1) * 32);
        }
        short8 af0 = *(const short8*)&sA[(wr * 32 + lid) * 40 + quad * 8];
        short8 af1 = *(const short8*)&sA[(wr * 32 + 16 + lid) * 40 + quad * 8];
        short8 bf0 = *(const short8*)&sB[(wc * 32 + lid) * 40 + quad * 8];
        short8 bf1 = *(const short8*)&sB[(wc * 32 + 16 + lid) * 40 + quad * 8];
        acc[0][0] = mfma16(af0, bf0, acc[0][0]);
        acc[0][1] = mfma16(af0, bf1, acc[0][1]);
        acc[1][0] = mfma16(af1, bf0, acc[1][0]);
        acc[1][1] = mfma16(af1, bf1, acc[1][1]);
    }
#pragma unroll
    for (int mt = 0; mt < 2; mt++)
#pragma unroll
        for (int nt = 0; nt < 2; nt++)
#pragma unroll
            for (int r = 0; r < 4; r++) {
                int grow = row0 + wr * 32 + mt * 16 + quad * 4 + r;
                int gcol = col0 + wc * 32 + nt * 16 + lid;
                float v = acc[mt][nt][r] + bias[gcol];
                int seq = grow >> 2, b = grow & 3;
                if (gcol < E) {
                    int c = gcol;
                    unsigned int cs = *(const unsigned int*)&pos[(((long)b * LKV + seq) * E + c) * 2];
                    float cv = bf2f((unsigned short)cs), sv = bf2f((unsigned short)(cs >> 16));
                    float p = __shfl_xor(v, 1);
                    float x2 = (c & 1) ? p : -p;
                    float rv = v * cv + x2 * sv;
                    kout[(((long)b * NH + (c >> 5)) * LKV + seq) * HD + (c & 31)] = f2bf(rv);
                } else {
                    int c = gcol - E;
                    vtout[(((long)b * NH + (c >> 5)) * HD + (c & 31)) * (long)LKV + seq] = f2bf(v);
                }
            }
}

// ---------------- flash attention, split-KV, no online max (scores bounded) ----------------
__global__ __launch_bounds__(256) void attn_k(
        const unsigned short* __restrict__ qb, const unsigned short* __restrict__ kb,
        const unsigned short* __restrict__ vtb, float* __restrict__ Opart,
        float* __restrict__ lpart) {
    __shared__ unsigned short sK[CK * 40];
    __shared__ unsigned short sVT[32 * 136];
    __shared__ unsigned short sPT[4 * CK * 36];
    const int t = threadIdx.x;
    const int lane = t & 63, wave = t >> 6, quad = lane >> 4, lid = lane & 15;
    const int qt0 = blockIdx.x * QT;
    const int bh = blockIdx.y;
    const int key0 = blockIdx.z * KSPAN;
    const unsigned short* kbase = kb + (long)bh * LKV * HD;
    const unsigned short* vbase = vtb + (long)bh * HD * LKV;
    short8 aq[2];
#pragma unroll
    for (int mf = 0; mf < 2; mf++)
        aq[mf] = *(const short8*)(qb + ((long)bh * LQ + qt0 + wave * 32 + mf * 16 + lid) * HD + quad * 8);
    float4v o[2][2];
#pragma unroll
    for (int i = 0; i < 2; i++) for (int j = 0; j < 2; j++) o[i][j] = (float4v){0.f, 0.f, 0.f, 0.f};
    float l[8] = {0.f, 0.f, 0.f, 0.f, 0.f, 0.f, 0.f, 0.f};
    const int krow = t >> 1, khalf = (t & 1) * 16;
    const int vrow = t >> 3, vkoff = (t & 7) * 16;
    unsigned short* myPT = &sPT[wave * CK * 36];
    for (int ck = key0; ck < key0 + KSPAN; ck += CK) {
        uint4 kv0 = *(const uint4*)(kbase + (long)(ck + krow) * HD + khalf);
        uint4 kv1 = *(const uint4*)(kbase + (long)(ck + krow) * HD + khalf + 8);
        uint4 vv0 = *(const uint4*)(vbase + (long)vrow * LKV + ck + vkoff);
        uint4 vv1 = *(const uint4*)(vbase + (long)vrow * LKV + ck + vkoff + 8);
        __syncthreads();
        *(uint4*)&sK[krow * 40 + khalf] = kv0;
        *(uint4*)&sK[krow * 40 + khalf + 8] = kv1;
        *(uint4*)&sVT[vrow * 136 + vkoff] = vv0;
        *(uint4*)&sVT[vrow * 136 + vkoff + 8] = vv1;
        __syncthreads();
#pragma unroll
        for (int nf = 0; nf < 8; nf++) {
            short8 bk = *(const short8*)&sK[(nf * 16 + lid) * 40 + quad * 8];
#pragma unroll
            for (int mf = 0; mf < 2; mf++) {
                float4v z = (float4v){0.f, 0.f, 0.f, 0.f};
                float4v s = mfma16(aq[mf], bk, z);
                float e0 = __expf(s[0]), e1 = __expf(s[1]);
                float e2 = __expf(s[2]), e3 = __expf(s[3]);
                l[mf * 4 + 0] += e0; l[mf * 4 + 1] += e1;
                l[mf * 4 + 2] += e2; l[mf * 4 + 3] += e3;
                uint2 pk;
                pk.x = pack2_rtz(e0, e1);
                pk.y = pack2_rtz(e2, e3);
                *(uint2*)&myPT[(nf * 16 + lid) * 36 + mf * 16 + quad * 4] = pk;
            }
        }
#pragma unroll
        for (int kb2 = 0; kb2 < 4; kb2++) {
            short8 bv0 = *(const short8*)&sVT[lid * 136 + kb2 * 32 + quad * 8];
            short8 bv1 = *(const short8*)&sVT[(16 + lid) * 136 + kb2 * 32 + quad * 8];
#pragma unroll
            for (int mf = 0; mf < 2; mf++) {
                short8 ap;
#pragma unroll
                for (int j = 0; j < 8; j++)
                    ap[j] = (short)myPT[(kb2 * 32 + quad * 8 + j) * 36 + mf * 16 + lid];
                o[mf][0] = mfma16(ap, bv0, o[mf][0]);
                o[mf][1] = mfma16(ap, bv1, o[mf][1]);
            }
        }
    }
#pragma unroll
    for (int i = 0; i < 8; i++) {
#pragma unroll
        for (int d = 1; d < 16; d <<= 1) l[i] += __shfl_xor(l[i], d);
    }
#pragma unroll
    for (int mf = 0; mf < 2; mf++)
#pragma unroll
        for (int r = 0; r < 4; r++) {
            long orow = ((long)blockIdx.z * 32 + bh) * LQ + qt0 + wave * 32 + mf * 16 + quad * 4 + r;
            Opart[orow * HD + lid] = o[mf][0][r];
            Opart[orow * HD + 16 + lid] = o[mf][1][r];
            if (lid == 0) lpart[orow] = l[mf * 4 + r];
        }
}

extern "C" void kernel_launch(void* const* d_in, const int* in_sizes, int n_in,
                              void* d_out, int out_size, void* d_ws, size_t ws_size,
                              hipStream_t stream) {
    (void)in_sizes; (void)n_in; (void)out_size; (void)ws_size;
    const float* query = (const float*)d_in[0];
    const float* value = (const float*)d_in[1];
    const float* qpos  = (const float*)d_in[2];
    const float* vpos  = (const float*)d_in[3];
    const float* Wqkv  = (const float*)d_in[4];
    const float* bqkv  = (const float*)d_in[5];
    const float* Wo    = (const float*)d_in[6];
    const float* bo    = (const float*)d_in[7];
    const float* g1    = (const float*)d_in[8];
    const float* be1   = (const float*)d_in[9];
    const float* W1    = (const float*)d_in[10];
    const float* b1    = (const float*)d_in[11];
    const float* W2    = (const float*)d_in[12];
    const float* b2    = (const float*)d_in[13];
    const float* g2    = (const float*)d_in[14];
    const float* be2   = (const float*)d_in[15];
    float* outp = (float*)d_out;

    char* w = (char*)d_ws;
    float*          cur     = (float*)(w + 0);                     // 2 MB
    unsigned short* cur_bf  = (unsigned short*)(w + (2l  << 20));  // 1 MB
    unsigned short* qbuf    = (unsigned short*)(w + (3l  << 20));  // 1 MB
    float*          xb      = (float*)(w + (4l  << 20));           // 2 MB
    unsigned short* xb_bf   = (unsigned short*)(w + (6l  << 20));  // 1 MB
    unsigned short* h1b_bf  = (unsigned short*)(w + (7l  << 20));  // 1 MB
    float*          lp      = (float*)(w + (8l  << 20));           // 64 KB
    float*          Opart   = (float*)(w + (9l  << 20));           // 8 MB
    unsigned short* val_bf  = (unsigned short*)(w + (17l << 20));  // 8 MB
    unsigned short* wqkv_bf = (unsigned short*)(w + (25l << 20));  // 1.5 MB
    unsigned short* wo_bf   = (unsigned short*)(w + (27l << 20));  // 0.5 MB
    unsigned short* w1_bf   = (unsigned short*)(w + (28l << 20));  // 0.5 MB
    unsigned short* w2_bf   = (unsigned short*)(w + (29l << 20));  // 0.5 MB
    unsigned short* qpos_bf = (unsigned short*)(w + (30l << 20));  // 2 MB
    unsigned short* vpos_bf = (unsigned short*)(w + (32l << 20));  // 16 MB
    unsigned short* kbuf    = (unsigned short*)(w + (48l << 20));  // 32 MB (4 layers)
    unsigned short* vtb     = (unsigned short*)(w + (80l << 20));  // 32 MB (4 layers)

    init_cur<<<2048, 256, 0, stream>>>(query, cur, cur_bf);
    pack_k<<<2048, 256, 0, stream>>>(value, val_bf);
    pack_k<<<384,  256, 0, stream>>>(Wqkv, wqkv_bf);
    pack_k<<<128,  256, 0, stream>>>(Wo, wo_bf);
    pack_k<<<128,  256, 0, stream>>>(W1, w1_bf);
    pack_k<<<128,  256, 0, stream>>>(W2, w2_bf);
    pack_k<<<512,  256, 0, stream>>>(qpos, qpos_bf);
    pack_k<<<4096, 256, 0, stream>>>(vpos, vpos_bf);

    // all 4 layers' KV projection in one launch (value is layer-invariant)
    qkv_kv<<<dim3(256, 8, NLAYER), 256, 0, stream>>>(val_bf, wqkv_bf, bqkv, vpos_bf, kbuf, vtb);

    for (int layer = 0; layer < NLAYER; layer++) {
        const unsigned short* Wl = wqkv_bf + (long)layer * 768 * 256;
        const float* bl = bqkv + (long)layer * 768;
        qkv_q<<<dim3(64, 4), 256, 0, stream>>>(cur_bf, Wl, bl, qpos_bf, qbuf);
        attn_k<<<dim3(LQ / QT, 32, SPLITS), 256, 0, stream>>>(
            qbuf, kbuf + (long)layer * 4194304, vtb + (long)layer * 4194304, Opart, lp);
        gemm_ln<1, 0><<<128, 256, 0, stream>>>(
            nullptr, Opart, lp, wo_bf + layer * 65536, bo + layer * 256,
            cur, g1 + layer * 256, be1 + layer * 256, xb, xb_bf, nullptr);
        gemm_k<<<dim3(64, 4), 256, 0, stream>>>(xb_bf, w1_bf + layer * 65536, b1 + layer * 256, h1b_bf);
        gemm_ln<0, 1><<<128, 256, 0, stream>>>(
            h1b_bf, nullptr, nullptr, w2_bf + layer * 65536, b2 + layer * 256,
            xb, g2 + layer * 256, be2 + layer * 256, cur, cur_bf,
            outp + (long)layer * LQ * NB * E);
    }
}

// Round 7
// 379.400 us; speedup vs baseline: 1.7614x; 1.1472x over previous
//
#include <hip/hip_runtime.h>
#include <hip/hip_bf16.h>

typedef __attribute__((ext_vector_type(8))) short short8;
typedef __attribute__((ext_vector_type(4))) float float4v;

#define LQ 512
#define NB 4
#define LKV 4096
#define E 256
#define NH 8
#define HD 32
#define NLAYER 4
#define QSCALE 0.17677669529663687f
#define SPLITS 8
#define KSPAN (LKV / SPLITS)
#define QT 128   // q rows per attn block
#define CK 128   // keys per attn chunk

// drain wave's LDS queue + forbid compiler reordering of LDS ops across this point.
// REQUIRED around wave-private cross-lane LDS reuse (myPT): data flows lane->lane via
// LDS with no barrier, and the compiler's per-thread alias reasoning may otherwise
// interleave the next chunk's ds_writes with in-flight ds_reads. [R6 post-timing race]
#define LDS_FENCE() asm volatile("s_waitcnt lgkmcnt(0)" ::: "memory")

__device__ __forceinline__ unsigned short f2bf(float f) {
    union { float f; unsigned int i; } x; x.f = f;
    unsigned int r = x.i + 0x7fffu + ((x.i >> 16) & 1u);
    return (unsigned short)(r >> 16);
}
__device__ __forceinline__ unsigned int pack2(float a, float b) {
    union { float f; unsigned int i; } xa, xb; xa.f = a; xb.f = b;
    unsigned int ra = xa.i + 0x7fffu + ((xa.i >> 16) & 1u);
    unsigned int rb = xb.i + 0x7fffu + ((xb.i >> 16) & 1u);
    return (ra >> 16) | (rb & 0xffff0000u);
}
__device__ __forceinline__ unsigned int pack2_rtz(float a, float b) {
    union { float f; unsigned int i; } xa, xb; xa.f = a; xb.f = b;
    return __builtin_amdgcn_perm(xb.i, xa.i, 0x07060302u);
}
__device__ __forceinline__ float bf2f(unsigned short u) {
    union { unsigned int i; float f; } x; x.i = ((unsigned int)u) << 16; return x.f;
}
__device__ __forceinline__ float4v mfma16(short8 a, short8 b, float4v c) {
    return __builtin_amdgcn_mfma_f32_16x16x32_bf16(a, b, c, 0, 0, 0);
}
__device__ __forceinline__ void pack_store8(const float* __restrict__ src,
                                            unsigned short* __restrict__ dst) {
    float4 a = *(const float4*)src;
    float4 b = *(const float4*)(src + 4);
    uint4 v;
    v.x = pack2(a.x, a.y); v.y = pack2(a.z, a.w);
    v.z = pack2(b.x, b.y); v.w = pack2(b.z, b.w);
    *(uint4*)dst = v;
}

// ================ one mega pre-pass: all packs + val b-major transpose + init ================
__global__ void pack_all(const float* __restrict__ value, const float* __restrict__ Wqkv,
                         const float* __restrict__ Wo, const float* __restrict__ W1,
                         const float* __restrict__ W2, const float* __restrict__ qpos,
                         const float* __restrict__ vpos, const float* __restrict__ query,
                         unsigned short* __restrict__ val_t, unsigned short* __restrict__ wqkv_bf,
                         unsigned short* __restrict__ wo_bf, unsigned short* __restrict__ w1_bf,
                         unsigned short* __restrict__ w2_bf, unsigned short* __restrict__ qpos_bf,
                         unsigned short* __restrict__ vpos_bf, float* __restrict__ cur,
                         unsigned short* __restrict__ cur_bf) {
    int bid = blockIdx.x;
    if (bid < 2048) {  // value -> val_t [b][seq][E] bf16
        long idx = ((long)bid * 256 + threadIdx.x) * 8;
        int ro = (int)(idx >> 8), e = (int)(idx & 255);
        int ri = ((ro & 4095) << 2) | (ro >> 12);   // in-row = seq*4 + b
        pack_store8(value + (long)ri * 256 + e, val_t + idx);
        return;
    }
    bid -= 2048;
    if (bid < 384) { long i = ((long)bid * 256 + threadIdx.x) * 8; pack_store8(Wqkv + i, wqkv_bf + i); return; }
    bid -= 384;
    if (bid < 128) { long i = ((long)bid * 256 + threadIdx.x) * 8; pack_store8(Wo + i, wo_bf + i); return; }
    bid -= 128;
    if (bid < 128) { long i = ((long)bid * 256 + threadIdx.x) * 8; pack_store8(W1 + i, w1_bf + i); return; }
    bid -= 128;
    if (bid < 128) { long i = ((long)bid * 256 + threadIdx.x) * 8; pack_store8(W2 + i, w2_bf + i); return; }
    bid -= 128;
    if (bid < 512) { long i = ((long)bid * 256 + threadIdx.x) * 8; pack_store8(qpos + i, qpos_bf + i); return; }
    bid -= 512;
    if (bid < 4096) { long i = ((long)bid * 256 + threadIdx.x) * 8; pack_store8(vpos + i, vpos_bf + i); return; }
    bid -= 4096;
    {   // init: cur = query f32 + bf16
        long i = ((long)bid * 256 + threadIdx.x) * 8;
        float4 a = *(const float4*)&query[i];
        float4 b = *(const float4*)&query[i + 4];
        *(float4*)&cur[i] = a;
        *(float4*)&cur[i + 4] = b;
        uint4 v;
        v.x = pack2(a.x, a.y); v.y = pack2(a.z, a.w);
        v.z = pack2(b.x, b.y); v.w = pack2(b.z, b.w);
        *(uint4*)&cur_bf[i] = v;
    }
}

// ================ GEMM (W1/relu): out_bf = relu(A_bf@W_bf^T + bias) ================
__global__ __launch_bounds__(256) void gemm_k(
        const unsigned short* __restrict__ A, const unsigned short* __restrict__ W,
        const float* __restrict__ bias, unsigned short* __restrict__ out_bf) {
    __shared__ unsigned short sA[32 * 264];
    __shared__ unsigned short sB[64 * 264];
    const int t = threadIdx.x;
    const int lane = t & 63, wave = t >> 6, quad = lane >> 4, lid = lane & 15;
    const int row0 = blockIdx.x * 32, col0 = blockIdx.y * 64;
    {
        int r = t >> 3, ks = (t & 7) * 32;
        const unsigned short* ap = A + (long)(row0 + r) * E + ks;
#pragma unroll
        for (int i = 0; i < 4; i++)
            *(uint4*)&sA[r * 264 + ks + i * 8] = *(const uint4*)(ap + i * 8);
    }
    {
        int r = t >> 2, ks = (t & 3) * 64;
        const unsigned short* wp = W + (long)(col0 + r) * E + ks;
#pragma unroll
        for (int i = 0; i < 8; i++)
            *(uint4*)&sB[r * 264 + ks + i * 8] = *(const uint4*)(wp + i * 8);
    }
    __syncthreads();
    float4v acc[2];
    acc[0] = (float4v){0.f, 0.f, 0.f, 0.f};
    acc[1] = (float4v){0.f, 0.f, 0.f, 0.f};
#pragma unroll
    for (int k0 = 0; k0 < E; k0 += 32) {
        short8 bf = *(const short8*)&sB[(wave * 16 + lid) * 264 + k0 + quad * 8];
        short8 af0 = *(const short8*)&sA[(lid) * 264 + k0 + quad * 8];
        short8 af1 = *(const short8*)&sA[(16 + lid) * 264 + k0 + quad * 8];
        acc[0] = mfma16(af0, bf, acc[0]);
        acc[1] = mfma16(af1, bf, acc[1]);
    }
#pragma unroll
    for (int mt = 0; mt < 2; mt++)
#pragma unroll
        for (int r = 0; r < 4; r++) {
            int grow = row0 + mt * 16 + quad * 4 + r;
            int gcol = col0 + wave * 16 + lid;
            float v = fmaxf(acc[mt][r] + bias[gcol], 0.f);
            out_bf[(long)grow * E + gcol] = f2bf(v);
        }
}

// ================ fused GEMM + bias + residual + LayerNorm ================
// M=16 rows/block (grid 128), N=256 across 4 waves x 4 nfrags. W streamed from L2 (R5 form).
template <int COMBINE, int OUT2>
__global__ __launch_bounds__(256, 1) void gemm_ln(
        const unsigned short* __restrict__ A,
        const float* __restrict__ Opart, const float* __restrict__ lp,
        const unsigned short* __restrict__ W, const float* __restrict__ bias,
        const float* __restrict__ res, const float* __restrict__ g,
        const float* __restrict__ bvec, float* __restrict__ outf,
        unsigned short* __restrict__ out_bf, float* __restrict__ outf2) {
    __shared__ unsigned short sA[16 * 264];
    __shared__ float lnS[4][16];
    __shared__ float lnQ[4][16];
    const int t = threadIdx.x;
    const int lane = t & 63, wave = t >> 6, quad = lane >> 4, lid = lane & 15;
    const int row0 = blockIdx.x * 16;
    {   // stage A tile: 16 rows x 256 cols bf16
        const int r = t >> 4, cseg = t & 15;
        if (COMBINE) {
            const int grow = row0 + r;
            const int seq = grow >> 2, b = grow & 3;
            const int h = cseg >> 1, dd = (cseg & 1) * 16;
            const int bh = b * 8 + h;
            float L = 0.f;
            float av[16];
#pragma unroll
            for (int j = 0; j < 16; j++) av[j] = 0.f;
#pragma unroll
            for (int s = 0; s < SPLITS; s++) {
                long rbase = (long)(s * 32 + bh) * 512 + seq;
                L += lp[rbase];
#pragma unroll
                for (int jj = 0; jj < 4; jj++) {
                    float4 p = *(const float4*)&Opart[rbase * 32 + dd + jj * 4];
                    av[jj * 4 + 0] += p.x; av[jj * 4 + 1] += p.y;
                    av[jj * 4 + 2] += p.z; av[jj * 4 + 3] += p.w;
                }
            }
            float inv = 1.f / L;
            uint4 u0, u1;
            u0.x = pack2(av[0] * inv, av[1] * inv);   u0.y = pack2(av[2] * inv, av[3] * inv);
            u0.z = pack2(av[4] * inv, av[5] * inv);   u0.w = pack2(av[6] * inv, av[7] * inv);
            u1.x = pack2(av[8] * inv, av[9] * inv);   u1.y = pack2(av[10] * inv, av[11] * inv);
            u1.z = pack2(av[12] * inv, av[13] * inv); u1.w = pack2(av[14] * inv, av[15] * inv);
            *(uint4*)&sA[r * 264 + cseg * 16] = u0;
            *(uint4*)&sA[r * 264 + cseg * 16 + 8] = u1;
        } else {
            const unsigned short* ap = A + (long)(row0 + r) * E + cseg * 16;
            *(uint4*)&sA[r * 264 + cseg * 16] = *(const uint4*)ap;
            *(uint4*)&sA[r * 264 + cseg * 16 + 8] = *(const uint4*)(ap + 8);
        }
    }
    __syncthreads();
    float4v acc[4];
#pragma unroll
    for (int nf = 0; nf < 4; nf++) acc[nf] = (float4v){0.f, 0.f, 0.f, 0.f};
#pragma unroll
    for (int k0 = 0; k0 < E; k0 += 32) {
        short8 af = *(const short8*)&sA[lid * 264 + k0 + quad * 8];
#pragma unroll
        for (int nf = 0; nf < 4; nf++) {
            short8 bf = *(const short8*)(W + (long)(wave * 64 + nf * 16 + lid) * E + k0 + quad * 8);
            acc[nf] = mfma16(af, bf, acc[nf]);
        }
    }
    float v[4][4];
    float sr[4], qr_[4];
#pragma unroll
    for (int r = 0; r < 4; r++) { sr[r] = 0.f; qr_[r] = 0.f; }
#pragma unroll
    for (int nf = 0; nf < 4; nf++) {
        int col = wave * 64 + nf * 16 + lid;
        float bcol = bias[col];
#pragma unroll
        for (int r = 0; r < 4; r++) {
            int grow = row0 + quad * 4 + r;
            float val = acc[nf][r] + bcol + res[(long)grow * E + col];
            v[nf][r] = val;
            sr[r] += val;
            qr_[r] += val * val;
        }
    }
#pragma unroll
    for (int r = 0; r < 4; r++) {
#pragma unroll
        for (int d = 1; d < 16; d <<= 1) {
            sr[r] += __shfl_xor(sr[r], d);
            qr_[r] += __shfl_xor(qr_[r], d);
        }
    }
    if (lid == 0) {
#pragma unroll
        for (int r = 0; r < 4; r++) {
            lnS[wave][quad * 4 + r] = sr[r];
            lnQ[wave][quad * 4 + r] = qr_[r];
        }
    }
    __syncthreads();
    float mean[4], rstd[4];
#pragma unroll
    for (int r = 0; r < 4; r++) {
        int row = quad * 4 + r;
        float S = lnS[0][row] + lnS[1][row] + lnS[2][row] + lnS[3][row];
        float Q = lnQ[0][row] + lnQ[1][row] + lnQ[2][row] + lnQ[3][row];
        float mu = S * (1.f / 256.f);
        float var = Q * (1.f / 256.f) - mu * mu;
        mean[r] = mu;
        rstd[r] = rsqrtf(var + 1e-5f);
    }
#pragma unroll
    for (int nf = 0; nf < 4; nf++) {
        int col = wave * 64 + nf * 16 + lid;
        float gc = g[col], bc = bvec[col];
#pragma unroll
        for (int r = 0; r < 4; r++) {
            int grow = row0 + quad * 4 + r;
            float xo = (v[nf][r] - mean[r]) * rstd[r] * gc + bc;
            outf[(long)grow * E + col] = xo;
            out_bf[(long)grow * E + col] = f2bf(xo);
            if (OUT2) outf2[(long)grow * E + col] = xo;
        }
    }
}

// ================ Q projection + scale + rotary -> qbuf[b][h][lq][hd] bf16 ================
__global__ __launch_bounds__(256) void qkv_q(
        const unsigned short* __restrict__ A, const unsigned short* __restrict__ W,
        const float* __restrict__ bias, const unsigned short* __restrict__ pos,
        unsigned short* __restrict__ qout) {
    __shared__ unsigned short sA[32 * 40];
    __shared__ unsigned short sB[64 * 40];
    const int t = threadIdx.x;
    const int lane = t & 63, wave = t >> 6, quad = lane >> 4, lid = lane & 15;
    const int row0 = blockIdx.x * 32, col0 = blockIdx.y * 64;
    const int sr = t >> 2, sk = (t & 3) * 8;
    const unsigned short* ap = A + (long)(row0 + sr) * E + sk;
    const unsigned short* wp = W + (long)(col0 + sr) * E + sk;
    uint4 av, bv;
    if (t < 128) av = *(const uint4*)ap;
    bv = *(const uint4*)wp;
    float4v acc[2];
    acc[0] = (float4v){0.f, 0.f, 0.f, 0.f};
    acc[1] = (float4v){0.f, 0.f, 0.f, 0.f};
#pragma unroll
    for (int ki = 0; ki < 8; ki++) {
        __syncthreads();
        if (t < 128) *(uint4*)&sA[sr * 40 + sk] = av;
        *(uint4*)&sB[sr * 40 + sk] = bv;
        __syncthreads();
        if (ki < 7) {
            if (t < 128) av = *(const uint4*)(ap + (ki + 1) * 32);
            bv = *(const uint4*)(wp + (ki + 1) * 32);
        }
        short8 af0 = *(const short8*)&sA[lid * 40 + quad * 8];
        short8 af1 = *(const short8*)&sA[(16 + lid) * 40 + quad * 8];
        short8 bf = *(const short8*)&sB[(wave * 16 + lid) * 40 + quad * 8];
        acc[0] = mfma16(af0, bf, acc[0]);
        acc[1] = mfma16(af1, bf, acc[1]);
    }
#pragma unroll
    for (int mt = 0; mt < 2; mt++)
#pragma unroll
        for (int r = 0; r < 4; r++) {
            int grow = row0 + mt * 16 + quad * 4 + r;
            int gcol = col0 + wave * 16 + lid;
            float v = (acc[mt][r] + bias[gcol]) * QSCALE;
            int seq = grow >> 2, b = grow & 3;
            int c = gcol;
            unsigned int cs = *(const unsigned int*)&pos[(((long)b * LQ + seq) * E + c) * 2];
            float cv = bf2f((unsigned short)cs), sv = bf2f((unsigned short)(cs >> 16));
            float p = __shfl_xor(v, 1);
            float x2 = (c & 1) ? p : -p;
            float rv = v * cv + x2 * sv;
            qout[(((long)b * NH + (c >> 5)) * LQ + seq) * HD + (c & 31)] = f2bf(rv);
        }
}

// ================ KV projection v2: A = val_t (b-major), BK=64, LDS-transposed V writes ================
__global__ __launch_bounds__(256) void qkv_kv(
        const unsigned short* __restrict__ A, const unsigned short* __restrict__ Wall,
        const float* __restrict__ ball, const unsigned short* __restrict__ pos,
        unsigned short* __restrict__ kall, unsigned short* __restrict__ vtall) {
    const int layer = blockIdx.z;
    const unsigned short* W = Wall + (long)layer * 768 * 256 + 256 * 256;
    const float* bias = ball + (long)layer * 768 + 256;
    unsigned short* kout = kall + (long)layer * 4194304;
    unsigned short* vtout = vtall + (long)layer * 4194304;
    __shared__ unsigned short sA[64 * 72];
    __shared__ unsigned short sB[64 * 72];
    __shared__ unsigned short sT[64 * 72];
    const int t = threadIdx.x;
    const int lane = t & 63, wave = t >> 6, quad = lane >> 4, lid = lane & 15;
    const int wr = wave >> 1, wc = wave & 1;
    const int row0 = blockIdx.x * 64, col0 = blockIdx.y * 64;
    const int b = row0 >> 12, seq0 = row0 & 4095;
    const int r = t >> 2, kk = (t & 3) * 16;
    const unsigned short* apg = A + (long)(row0 + r) * E + kk;
    const unsigned short* wpg = W + (long)(col0 + r) * E + kk;
    uint4 a0 = *(const uint4*)apg,        a1 = *(const uint4*)(apg + 8);
    uint4 b0 = *(const uint4*)wpg,        b1 = *(const uint4*)(wpg + 8);
    float4v acc[2][2];
    for (int i = 0; i < 2; i++) for (int j = 0; j < 2; j++) acc[i][j] = (float4v){0.f, 0.f, 0.f, 0.f};
#pragma unroll
    for (int ki = 0; ki < 4; ki++) {
        __syncthreads();
        *(uint4*)&sA[r * 72 + kk] = a0; *(uint4*)&sA[r * 72 + kk + 8] = a1;
        *(uint4*)&sB[r * 72 + kk] = b0; *(uint4*)&sB[r * 72 + kk + 8] = b1;
        __syncthreads();
        if (ki < 3) {
            a0 = *(const uint4*)(apg + (ki + 1) * 64); a1 = *(const uint4*)(apg + (ki + 1) * 64 + 8);
            b0 = *(const uint4*)(wpg + (ki + 1) * 64); b1 = *(const uint4*)(wpg + (ki + 1) * 64 + 8);
        }
#pragma unroll
        for (int kf = 0; kf < 2; kf++) {
            const int ko = kf * 32 + quad * 8;
            short8 af0 = *(const short8*)&sA[(wr * 32 + lid) * 72 + ko];
            short8 af1 = *(const short8*)&sA[(wr * 32 + 16 + lid) * 72 + ko];
            short8 bf0 = *(const short8*)&sB[(wc * 32 + lid) * 72 + ko];
            short8 bf1 = *(const short8*)&sB[(wc * 32 + 16 + lid) * 72 + ko];
            acc[0][0] = mfma16(af0, bf0, acc[0][0]);
            acc[0][1] = mfma16(af0, bf1, acc[0][1]);
            acc[1][0] = mfma16(af1, bf0, acc[1][0]);
            acc[1][1] = mfma16(af1, bf1, acc[1][1]);
        }
    }
    if (col0 < 256) {  // ---- K half: rotary, direct stores ----
#pragma unroll
        for (int mt = 0; mt < 2; mt++)
#pragma unroll
            for (int nt = 0; nt < 2; nt++)
#pragma unroll
                for (int rr = 0; rr < 4; rr++) {
                    int m = wr * 32 + mt * 16 + quad * 4 + rr;
                    int c = col0 + wc * 32 + nt * 16 + lid;
                    int seq = seq0 + m;
                    float v = acc[mt][nt][rr] + bias[c];
                    unsigned int cs = *(const unsigned int*)&pos[(((long)b * LKV + seq) * E + c) * 2];
                    float cv = bf2f((unsigned short)cs), sv = bf2f((unsigned short)(cs >> 16));
                    float p = __shfl_xor(v, 1);
                    float x2 = (c & 1) ? p : -p;
                    float rv = v * cv + x2 * sv;
                    kout[(((long)b * NH + (c >> 5)) * LKV + seq) * HD + (c & 31)] = f2bf(rv);
                }
    } else {           // ---- V half: LDS transpose then coalesced writes ----
#pragma unroll
        for (int mt = 0; mt < 2; mt++)
#pragma unroll
            for (int nt = 0; nt < 2; nt++) {
                int cl = wc * 32 + nt * 16 + lid;
                int so = wr * 32 + mt * 16 + quad * 4;
                float bcol = bias[col0 + cl];
                uint2 pw;
                pw.x = pack2(acc[mt][nt][0] + bcol, acc[mt][nt][1] + bcol);
                pw.y = pack2(acc[mt][nt][2] + bcol, acc[mt][nt][3] + bcol);
                *(uint2*)&sT[cl * 72 + so] = pw;
            }
        __syncthreads();
        const int cl = t >> 2, sc = (t & 3) * 16;
        uint4 u0 = *(const uint4*)&sT[cl * 72 + sc];
        uint4 u1 = *(const uint4*)&sT[cl * 72 + sc + 8];
        int cg = (col0 - 256) + cl;
        unsigned short* dst = vtout + (((long)b * NH + (cg >> 5)) * HD + (cg & 31)) * (long)LKV + seq0 + sc;
        *(uint4*)dst = u0;
        *(uint4*)(dst + 8) = u1;
    }
}

// ================ flash attention, split-KV(8), no online max, fenced sPT reuse ================
__global__ __launch_bounds__(256) void attn_k(
        const unsigned short* __restrict__ qb, const unsigned short* __restrict__ kb,
        const unsigned short* __restrict__ vtb, float* __restrict__ Opart,
        float* __restrict__ lpart) {
    __shared__ unsigned short sK[CK * 40];       // 10.0 KB
    __shared__ unsigned short sVT[32 * 136];     // 8.5 KB
    __shared__ unsigned short sPT[4 * 64 * 36];  // 18.0 KB (per-wave, 64-key sub-chunk)
    const int t = threadIdx.x;
    const int lane = t & 63, wave = t >> 6, quad = lane >> 4, lid = lane & 15;
    const int qt0 = blockIdx.x * QT;
    const int bh = blockIdx.y;
    const int key0 = blockIdx.z * KSPAN;
    const unsigned short* kbase = kb + (long)bh * LKV * HD;
    const unsigned short* vbase = vtb + (long)bh * HD * LKV;
    short8 aq[2];
#pragma unroll
    for (int mf = 0; mf < 2; mf++)
        aq[mf] = *(const short8*)(qb + ((long)bh * LQ + qt0 + wave * 32 + mf * 16 + lid) * HD + quad * 8);
    float4v o[2][2];
#pragma unroll
    for (int i = 0; i < 2; i++) for (int j = 0; j < 2; j++) o[i][j] = (float4v){0.f, 0.f, 0.f, 0.f};
    float l[8] = {0.f, 0.f, 0.f, 0.f, 0.f, 0.f, 0.f, 0.f};
    const int krow = t >> 1, khalf = (t & 1) * 16;
    const int vrow = t >> 3, vkoff = (t & 7) * 16;
    unsigned short* myPT = &sPT[wave * 64 * 36];
    uint4 kv0 = *(const uint4*)(kbase + (long)(key0 + krow) * HD + khalf);
    uint4 kv1 = *(const uint4*)(kbase + (long)(key0 + krow) * HD + khalf + 8);
    uint4 vv0 = *(const uint4*)(vbase + (long)vrow * LKV + key0 + vkoff);
    uint4 vv1 = *(const uint4*)(vbase + (long)vrow * LKV + key0 + vkoff + 8);
    for (int ck = key0; ck < key0 + KSPAN; ck += CK) {
        __syncthreads();
        *(uint4*)&sK[krow * 40 + khalf] = kv0;
        *(uint4*)&sK[krow * 40 + khalf + 8] = kv1;
        *(uint4*)&sVT[vrow * 136 + vkoff] = vv0;
        *(uint4*)&sVT[vrow * 136 + vkoff + 8] = vv1;
        __syncthreads();
        if (ck + CK < key0 + KSPAN) {   // prefetch next chunk
            kv0 = *(const uint4*)(kbase + (long)(ck + CK + krow) * HD + khalf);
            kv1 = *(const uint4*)(kbase + (long)(ck + CK + krow) * HD + khalf + 8);
            vv0 = *(const uint4*)(vbase + (long)vrow * LKV + ck + CK + vkoff);
            vv1 = *(const uint4*)(vbase + (long)vrow * LKV + ck + CK + vkoff + 8);
        }
#pragma unroll
        for (int half = 0; half < 2; half++) {
#pragma unroll
            for (int nf = 0; nf < 4; nf++) {
                short8 bk = *(const short8*)&sK[(half * 64 + nf * 16 + lid) * 40 + quad * 8];
#pragma unroll
                for (int mf = 0; mf < 2; mf++) {
                    float4v z = (float4v){0.f, 0.f, 0.f, 0.f};
                    float4v s = mfma16(aq[mf], bk, z);
                    float e0 = __expf(s[0]), e1 = __expf(s[1]);
                    float e2 = __expf(s[2]), e3 = __expf(s[3]);
                    l[mf * 4 + 0] += e0; l[mf * 4 + 1] += e1;
                    l[mf * 4 + 2] += e2; l[mf * 4 + 3] += e3;
                    uint2 pk;
                    pk.x = pack2_rtz(e0, e1);
                    pk.y = pack2_rtz(e2, e3);
                    *(uint2*)&myPT[(nf * 16 + lid) * 36 + mf * 16 + quad * 4] = pk;
                }
            }
            LDS_FENCE();   // P writes drained before cross-lane reads (no barrier here!)
#pragma unroll
            for (int kb2 = 0; kb2 < 2; kb2++) {
                short8 bv0 = *(const short8*)&sVT[lid * 136 + half * 64 + kb2 * 32 + quad * 8];
                short8 bv1 = *(const short8*)&sVT[(16 + lid) * 136 + half * 64 + kb2 * 32 + quad * 8];
#pragma unroll
                for (int mf = 0; mf < 2; mf++) {
                    short8 ap;
#pragma unroll
                    for (int j = 0; j < 8; j++)
                        ap[j] = (short)myPT[(kb2 * 32 + quad * 8 + j) * 36 + mf * 16 + lid];
                    o[mf][0] = mfma16(ap, bv0, o[mf][0]);
                    o[mf][1] = mfma16(ap, bv1, o[mf][1]);
                }
            }
            LDS_FENCE();   // P reads drained before next half overwrites myPT
        }
    }
#pragma unroll
    for (int i = 0; i < 8; i++) {
#pragma unroll
        for (int d = 1; d < 16; d <<= 1) l[i] += __shfl_xor(l[i], d);
    }
#pragma unroll
    for (int mf = 0; mf < 2; mf++)
#pragma unroll
        for (int r = 0; r < 4; r++) {
            long orow = ((long)blockIdx.z * 32 + bh) * LQ + qt0 + wave * 32 + mf * 16 + quad * 4 + r;
            Opart[orow * HD + lid] = o[mf][0][r];
            Opart[orow * HD + 16 + lid] = o[mf][1][r];
            if (lid == 0) lpart[orow] = l[mf * 4 + r];
        }
}

extern "C" void kernel_launch(void* const* d_in, const int* in_sizes, int n_in,
                              void* d_out, int out_size, void* d_ws, size_t ws_size,
                              hipStream_t stream) {
    (void)in_sizes; (void)n_in; (void)out_size; (void)ws_size;
    const float* query = (const float*)d_in[0];
    const float* value = (const float*)d_in[1];
    const float* qpos  = (const float*)d_in[2];
    const float* vpos  = (const float*)d_in[3];
    const float* Wqkv  = (const float*)d_in[4];
    const float* bqkv  = (const float*)d_in[5];
    const float* Wo    = (const float*)d_in[6];
    const float* bo    = (const float*)d_in[7];
    const float* g1    = (const float*)d_in[8];
    const float* be1   = (const float*)d_in[9];
    const float* W1    = (const float*)d_in[10];
    const float* b1    = (const float*)d_in[11];
    const float* W2    = (const float*)d_in[12];
    const float* b2    = (const float*)d_in[13];
    const float* g2    = (const float*)d_in[14];
    const float* be2   = (const float*)d_in[15];
    float* outp = (float*)d_out;

    char* w = (char*)d_ws;
    float*          cur     = (float*)(w + 0);                     // 2 MB
    unsigned short* cur_bf  = (unsigned short*)(w + (2l  << 20));  // 1 MB
    unsigned short* qbuf    = (unsigned short*)(w + (3l  << 20));  // 1 MB
    float*          xb      = (float*)(w + (4l  << 20));           // 2 MB
    unsigned short* xb_bf   = (unsigned short*)(w + (6l  << 20));  // 1 MB
    unsigned short* h1b_bf  = (unsigned short*)(w + (7l  << 20));  // 1 MB
    float*          lp      = (float*)(w + (8l  << 20));           // 512 KB
    float*          Opart   = (float*)(w + (9l  << 20));           // 16 MB
    unsigned short* val_t   = (unsigned short*)(w + (25l << 20));  // 8 MB  [b][seq][E]
    unsigned short* wqkv_bf = (unsigned short*)(w + (33l << 20));  // 1.5 MB
    unsigned short* wo_bf   = (unsigned short*)(w + (35l << 20));  // 0.5 MB
    unsigned short* w1_bf   = (unsigned short*)(w + (36l << 20));  // 0.5 MB
    unsigned short* w2_bf   = (unsigned short*)(w + (37l << 20));  // 0.5 MB
    unsigned short* qpos_bf = (unsigned short*)(w + (38l << 20));  // 2 MB
    unsigned short* vpos_bf = (unsigned short*)(w + (40l << 20));  // 16 MB
    unsigned short* kbuf    = (unsigned short*)(w + (56l << 20));  // 32 MB (4 layers)
    unsigned short* vtb     = (unsigned short*)(w + (88l << 20));  // 32 MB (4 layers)

    pack_all<<<7680, 256, 0, stream>>>(value, Wqkv, Wo, W1, W2, qpos, vpos, query,
                                       val_t, wqkv_bf, wo_bf, w1_bf, w2_bf, qpos_bf,
                                       vpos_bf, cur, cur_bf);

    // all 4 layers' KV projection in one launch (value is layer-invariant)
    qkv_kv<<<dim3(256, 8, NLAYER), 256, 0, stream>>>(val_t, wqkv_bf, bqkv, vpos_bf, kbuf, vtb);

    for (int layer = 0; layer < NLAYER; layer++) {
        const unsigned short* Wl = wqkv_bf + (long)layer * 768 * 256;
        const float* bl = bqkv + (long)layer * 768;
        qkv_q<<<dim3(64, 4), 256, 0, stream>>>(cur_bf, Wl, bl, qpos_bf, qbuf);
        attn_k<<<dim3(LQ / QT, 32, SPLITS), 256, 0, stream>>>(
            qbuf, kbuf + (long)layer * 4194304, vtb + (long)layer * 4194304, Opart, lp);
        gemm_ln<1, 0><<<128, 256, 0, stream>>>(
            nullptr, Opart, lp, wo_bf + layer * 65536, bo + layer * 256,
            cur, g1 + layer * 256, be1 + layer * 256, xb, xb_bf, nullptr);
        gemm_k<<<dim3(64, 4), 256, 0, stream>>>(xb_bf, w1_bf + layer * 65536, b1 + layer * 256, h1b_bf);
        gemm_ln<0, 1><<<128, 256, 0, stream>>>(
            h1b_bf, nullptr, nullptr, w2_bf + layer * 65536, b2 + layer * 256,
            xb, g2 + layer * 256, be2 + layer * 256, cur, cur_bf,
            outp + (long)layer * LQ * NB * E);
    }
}